// Round 6
// baseline (67.857 us; speedup 1.0000x reference)
//
#include <hip/hip_runtime.h>

#define THREADS 256
#define R 4                       // queries per thread (register-resident)
#define QCHUNK (THREADS * R)      // 1024 queries per block
#define TCHUNK 256                // targets streamed per block (uniform s_loads)

// ws layout: [0, 2*B*N) min-sqdist uint bits | 64 float partials | pad | float4 tprep[2*B*N]

// Prep: tprep[dir][b][j] = (-2gx, -2gy, -2gz, |g|^2), and init minsq to +inf.
__global__ __launch_bounds__(THREADS) void prep_kernel(
    const float* __restrict__ pred, const float* __restrict__ gt,
    float4* __restrict__ tprep, unsigned int* __restrict__ minsq, int N, int B)
{
    int i = blockIdx.x * THREADS + threadIdx.x;   // [0, 2*B*N)
    int dir = i / (B * N);
    int rem = i - dir * B * N;
    int b = rem / N, j = rem - b * N;
    const float* t = (dir ? pred : gt) + (size_t)b * 3 * N;
    float gx = t[j], gy = t[N + j], gz = t[2 * N + j];
    tprep[i] = make_float4(-2.f * gx, -2.f * gy, -2.f * gz,
                           fmaf(gx, gx, fmaf(gy, gy, gz * gz)));
    minsq[i] = 0x7F800000u;
}

// d2 = |p|^2 + (|g|^2 - 2 p.g); |p|^2 added after the loop.
// PREP=true: targets from tprep (uniform float4 stream -> scalar loads, no LDS).
// PREP=false: targets rebuilt on the fly from raw coords (no extra ws needed).
template <bool PREP>
__global__ __launch_bounds__(THREADS) void nn_min_kernel(
    const float* __restrict__ pred,   // [B,3,N]
    const float* __restrict__ gt,     // [B,3,N]
    const float4* __restrict__ tprep, // [2,B,N] or unused
    unsigned int* __restrict__ minsq, // [2,B,N] as uint bits
    int N, int B, int nQC, int nTC, int blocksPerDir)
{
    int blk = blockIdx.x;
    int dir = blk / blocksPerDir;
    blk -= dir * blocksPerDir;
    int tc = blk % nTC;
    int qc = (blk / nTC) % nQC;
    int b  = blk / (nTC * nQC);

    const float* q = (dir ? gt : pred) + (size_t)b * 3 * N;
    const float* t = (dir ? pred : gt) + (size_t)b * 3 * N + tc * TCHUNK;
    const float4* tt = tprep + ((size_t)dir * B + b) * N + tc * TCHUNK;

    float px[R], py[R], pz[R], p2[R], mn[R];
    int q0 = qc * QCHUNK + threadIdx.x;
    #pragma unroll
    for (int r = 0; r < R; ++r) {
        int qi = q0 + r * THREADS;
        px[r] = q[qi];
        py[r] = q[N + qi];
        pz[r] = q[2 * N + qi];
        p2[r] = fmaf(px[r], px[r], fmaf(py[r], py[r], pz[r] * pz[r]));
        mn[r] = 3.0e38f;
    }
    if (!PREP) {
        // fold the -2 into the query registers instead of the targets
        #pragma unroll
        for (int r = 0; r < R; ++r) { px[r] *= -2.f; py[r] *= -2.f; pz[r] *= -2.f; }
    }

    if (PREP) {
        float4 c0 = tt[0], c1 = tt[1], c2 = tt[2], c3 = tt[3];
        for (int j = 0; j < TCHUNK; j += 4) {
            int jn = (j + 4) & (TCHUNK - 1);  // wraps on last iter; values unused
            float4 n0 = tt[jn], n1 = tt[jn + 1], n2 = tt[jn + 2], n3 = tt[jn + 3];
            #pragma unroll
            for (int r = 0; r < R; ++r) {
                float d0 = fmaf(c0.x, px[r], fmaf(c0.y, py[r], fmaf(c0.z, pz[r], c0.w)));
                float d1 = fmaf(c1.x, px[r], fmaf(c1.y, py[r], fmaf(c1.z, pz[r], c1.w)));
                float d2 = fmaf(c2.x, px[r], fmaf(c2.y, py[r], fmaf(c2.z, pz[r], c2.w)));
                float d3 = fmaf(c3.x, px[r], fmaf(c3.y, py[r], fmaf(c3.z, pz[r], c3.w)));
                mn[r] = fminf(fminf(d0, d1), mn[r]);   // v_min3_f32
                mn[r] = fminf(fminf(d2, d3), mn[r]);   // v_min3_f32
            }
            c0 = n0; c1 = n1; c2 = n2; c3 = n3;
        }
    } else {
        for (int j = 0; j < TCHUNK; j += 4) {
            float4 gx4 = *(const float4*)&t[j];
            float4 gy4 = *(const float4*)&t[N + j];
            float4 gz4 = *(const float4*)&t[2 * N + j];
            float g2_0 = fmaf(gx4.x, gx4.x, fmaf(gy4.x, gy4.x, gz4.x * gz4.x));
            float g2_1 = fmaf(gx4.y, gx4.y, fmaf(gy4.y, gy4.y, gz4.y * gz4.y));
            float g2_2 = fmaf(gx4.z, gx4.z, fmaf(gy4.z, gy4.z, gz4.z * gz4.z));
            float g2_3 = fmaf(gx4.w, gx4.w, fmaf(gy4.w, gy4.w, gz4.w * gz4.w));
            #pragma unroll
            for (int r = 0; r < R; ++r) {
                float d0 = fmaf(gx4.x, px[r], fmaf(gy4.x, py[r], fmaf(gz4.x, pz[r], g2_0)));
                float d1 = fmaf(gx4.y, px[r], fmaf(gy4.y, py[r], fmaf(gz4.y, pz[r], g2_1)));
                float d2 = fmaf(gx4.z, px[r], fmaf(gy4.z, py[r], fmaf(gz4.z, pz[r], g2_2)));
                float d3 = fmaf(gx4.w, px[r], fmaf(gy4.w, py[r], fmaf(gz4.w, pz[r], g2_3)));
                mn[r] = fminf(fminf(d0, d1), mn[r]);
                mn[r] = fminf(fminf(d2, d3), mn[r]);
            }
        }
    }

    unsigned int* mb = minsq + ((size_t)dir * B + b) * N;
    #pragma unroll
    for (int r = 0; r < R; ++r) {
        float d2 = fmaxf(mn[r] + p2[r], 0.f);  // clamp: keep uint-bit ordering valid
        atomicMin(&mb[q0 + r * THREADS], __float_as_uint(d2));
    }
}

// Stage 1: 64 blocks x 256 threads -> 64 partial sums of sqrt(min+eps)
__global__ __launch_bounds__(THREADS) void reduce1_kernel(
    const unsigned int* __restrict__ minsq, float* __restrict__ partials, int total)
{
    __shared__ float sdata[THREADS];
    float s = 0.f;
    for (int i = blockIdx.x * THREADS + threadIdx.x; i < total; i += gridDim.x * THREADS) {
        float v = __uint_as_float(minsq[i]);
        s += sqrtf(v + 1e-8f);
    }
    sdata[threadIdx.x] = s;
    __syncthreads();
    for (int off = THREADS / 2; off > 0; off >>= 1) {
        if (threadIdx.x < off) sdata[threadIdx.x] += sdata[threadIdx.x + off];
        __syncthreads();
    }
    if (threadIdx.x == 0) partials[blockIdx.x] = sdata[0];
}

// Stage 2: one wave reduces 64 partials.
__global__ __launch_bounds__(64) void reduce2_kernel(
    const float* __restrict__ partials, float* __restrict__ out, float inv)
{
    float s = partials[threadIdx.x];
    #pragma unroll
    for (int off = 32; off > 0; off >>= 1) s += __shfl_down(s, off);
    if (threadIdx.x == 0) out[0] = s * inv;
}

extern "C" void kernel_launch(void* const* d_in, const int* in_sizes, int n_in,
                              void* d_out, int out_size, void* d_ws, size_t ws_size,
                              hipStream_t stream) {
    const float* pred = (const float*)d_in[0];
    const float* gt   = (const float*)d_in[1];
    const int N = 8192;
    const int B = in_sizes[0] / (3 * N);   // = 4

    unsigned int* minsq = (unsigned int*)d_ws;            // 2*B*N uints = 256 KB
    int total = 2 * B * N;
    float* partials = (float*)(minsq + total);            // 64 floats
    // tprep at 512 KB offset (16B aligned), needs 2*B*N*16 = 1 MB
    float4* tprep = (float4*)((char*)d_ws + (512 << 10));
    size_t need = (512 << 10) + (size_t)total * sizeof(float4);

    int nQC = N / QCHUNK;              // 8
    int nTC = N / TCHUNK;              // 32
    int blocksPerDir = B * nQC * nTC;  // 1024

    if (ws_size >= need) {
        prep_kernel<<<total / THREADS, THREADS, 0, stream>>>(pred, gt, tprep, minsq, N, B);
        nn_min_kernel<true><<<2 * blocksPerDir, THREADS, 0, stream>>>(
            pred, gt, tprep, minsq, N, B, nQC, nTC, blocksPerDir);
    } else {
        hipMemsetAsync(minsq, 0x7F, (size_t)total * sizeof(unsigned int), stream);
        nn_min_kernel<false><<<2 * blocksPerDir, THREADS, 0, stream>>>(
            pred, gt, tprep, minsq, N, B, nQC, nTC, blocksPerDir);
    }

    reduce1_kernel<<<64, THREADS, 0, stream>>>(minsq, partials, total);
    reduce2_kernel<<<1, 64, 0, stream>>>(partials, (float*)d_out, 1.0f / (B * N));
}

// Round 7
// 53.614 us; speedup vs baseline: 1.2657x; 1.2657x over previous
//
#include <hip/hip_runtime.h>

#define THREADS 256
#define NB 4                 // batches
#define NPTS 8192            // points per cloud
#define NT (NPTS / 32)       // 256 MFMA tiles per (dir,b)

typedef __attribute__((ext_vector_type(8))) short short8;   // 8 bf16 = 4 VGPR
typedef __attribute__((ext_vector_type(16))) float f32x16;  // MFMA 32x32 acc

// ws layout (bytes):
#define OFF_P2    (256 << 10)
#define OFF_PART  (512 << 10)
#define OFF_SA    (1 << 20)   // target frags: 2*4*256*64*16B = 2 MB
#define OFF_SB    (3 << 20)   // query frags: 2 MB
#define WS_NEED   (5 << 20)

__device__ inline unsigned short f2b(float f) {  // f32 -> bf16 RNE (no NaN inputs here)
    unsigned u = __float_as_uint(f);
    return (unsigned short)((u + 0x7FFFu + ((u >> 16) & 1u)) >> 16);
}
__device__ inline float b2f(unsigned short h) {
    return __uint_as_float(((unsigned)h) << 16);
}

// Pack fragment streams in EXACT mfma_32x32x16_bf16 lane order.
// A-operand (targets, rows): lane l -> row = l&31, k-group = l>>5 (8 bf16).
// K slots: [ghx ghy ghz glx gly glz ghx ghy | ghz g2h g2l 0 0 0 0 0]
// B-operand (queries, cols): lane l -> col = l&31, k-group = l>>5.
// K slots: [ahx ahy ahz ahx ahy ahz alx aly | alz 1 1 0 0 0 0 0], a = split(-2p)
// => acc[target][query] = |g|^2 - 2 p.g   (add |p|^2 afterwards)
__global__ __launch_bounds__(THREADS) void prep_kernel(
    const float* __restrict__ pred, const float* __restrict__ gt,
    short8* __restrict__ sA, short8* __restrict__ sB,
    float* __restrict__ p2s, unsigned int* __restrict__ minsq, int N)
{
    int i = blockIdx.x * THREADS + threadIdx.x;   // [0, 2*NB*N)
    int dir = i / (NB * N);
    int rem = i - dir * NB * N;
    int b = rem / N, idx = rem - b * N;
    const float* q = (dir ? gt : pred) + (size_t)b * 3 * N;  // queries this dir
    const float* t = (dir ? pred : gt) + (size_t)b * 3 * N;  // targets this dir

    size_t ebase = ((size_t)(dir * NB + b)) * NT * 64;
    int tile = idx >> 5, c = idx & 31;

    // target fragment
    float gx = t[idx], gy = t[N + idx], gz = t[2 * N + idx];
    unsigned short ghx = f2b(gx), ghy = f2b(gy), ghz = f2b(gz);
    unsigned short glx = f2b(gx - b2f(ghx)), gly = f2b(gy - b2f(ghy)), glz = f2b(gz - b2f(ghz));
    float g2 = fmaf(gx, gx, fmaf(gy, gy, gz * gz));
    unsigned short g2h = f2b(g2), g2l = f2b(g2 - b2f(g2h));
    short8 ta0, ta1;
    ta0[0]=(short)ghx; ta0[1]=(short)ghy; ta0[2]=(short)ghz; ta0[3]=(short)glx;
    ta0[4]=(short)gly; ta0[5]=(short)glz; ta0[6]=(short)ghx; ta0[7]=(short)ghy;
    ta1[0]=(short)ghz; ta1[1]=(short)g2h; ta1[2]=(short)g2l; ta1[3]=0;
    ta1[4]=0; ta1[5]=0; ta1[6]=0; ta1[7]=0;
    sA[ebase + (size_t)tile * 64 + c]      = ta0;
    sA[ebase + (size_t)tile * 64 + 32 + c] = ta1;

    // query fragment: split of (-2p)
    float px = q[idx], py = q[N + idx], pz = q[2 * N + idx];
    float ax = -2.f * px, ay = -2.f * py, az = -2.f * pz;
    unsigned short ahx = f2b(ax), ahy = f2b(ay), ahz = f2b(az);
    unsigned short alx = f2b(ax - b2f(ahx)), aly = f2b(ay - b2f(ahy)), alz = f2b(az - b2f(ahz));
    const short ONE = (short)0x3F80;
    short8 qb0, qb1;
    qb0[0]=(short)ahx; qb0[1]=(short)ahy; qb0[2]=(short)ahz; qb0[3]=(short)ahx;
    qb0[4]=(short)ahy; qb0[5]=(short)ahz; qb0[6]=(short)alx; qb0[7]=(short)aly;
    qb1[0]=(short)alz; qb1[1]=ONE; qb1[2]=ONE; qb1[3]=0;
    qb1[4]=0; qb1[5]=0; qb1[6]=0; qb1[7]=0;
    sB[ebase + (size_t)tile * 64 + c]      = qb0;
    sB[ebase + (size_t)tile * 64 + 32 + c] = qb1;

    p2s[i] = fmaf(px, px, fmaf(py, py, pz * pz));
    minsq[i] = 0x7F800000u;   // +inf bits
}

#define MFMA(a, b, c) __builtin_amdgcn_mfma_f32_32x32x16_bf16(a, b, c, 0, 0, 0)

// min over 32 acc values (2 tiles x 16 regs, all candidate targets) + running min.
__device__ inline float min32(f32x16 x, f32x16 y, float r) {
    float m = fminf(r, fminf(x[0], y[0]));   // v_min3
    #pragma unroll
    for (int i = 1; i < 16; ++i) m = fminf(m, fminf(x[i], y[i]));  // 15x v_min3
    return m;
}

// wave = (dir, b, qg, jc): 4 query tiles (128 queries) x 32 target tiles.
__global__ __launch_bounds__(THREADS) void nn_mfma_kernel(
    const short8* __restrict__ sA, const short8* __restrict__ sB,
    const float* __restrict__ p2s, unsigned int* __restrict__ minsq, int N)
{
    int w = blockIdx.x * 4 + (threadIdx.x >> 6);   // [0, 4096)
    int lane = threadIdx.x & 63;
    int dir = w >> 11;
    int b   = (w >> 9) & 3;
    int qg  = (w >> 3) & 63;
    int jc  = w & 7;

    size_t ebase = ((size_t)(dir * NB + b)) * NT * 64;
    const short8* A  = sA + ebase;
    const short8* Bq = sB + ebase;

    short8 bq0 = Bq[(size_t)(qg * 4 + 0) * 64 + lane];
    short8 bq1 = Bq[(size_t)(qg * 4 + 1) * 64 + lane];
    short8 bq2 = Bq[(size_t)(qg * 4 + 2) * 64 + lane];
    short8 bq3 = Bq[(size_t)(qg * 4 + 3) * 64 + lane];

    f32x16 z;
    #pragma unroll
    for (int i = 0; i < 16; ++i) z[i] = 0.f;

    float rmin0 = 3.0e38f, rmin1 = 3.0e38f, rmin2 = 3.0e38f, rmin3 = 3.0e38f;

    const short8* ap = A + (size_t)(jc * 32) * 64 + lane;
    for (int t = 0; t < 32; t += 2) {
        short8 a0 = ap[0];
        short8 a1 = ap[64];
        ap += 128;
        f32x16 c0, c1;
        c0 = MFMA(a0, bq0, z); c1 = MFMA(a1, bq0, z);
        rmin0 = min32(c0, c1, rmin0);
        c0 = MFMA(a0, bq1, z); c1 = MFMA(a1, bq1, z);
        rmin1 = min32(c0, c1, rmin1);
        c0 = MFMA(a0, bq2, z); c1 = MFMA(a1, bq2, z);
        rmin2 = min32(c0, c1, rmin2);
        c0 = MFMA(a0, bq3, z); c1 = MFMA(a1, bq3, z);
        rmin3 = min32(c0, c1, rmin3);
    }

    // acc col = lane&31 (query); halves differ only in target rows -> xor-32 merge.
    int qbase = (dir * NB + b) * N + qg * 128;
    #pragma unroll
    for (int qi = 0; qi < 4; ++qi) {
        float v = qi == 0 ? rmin0 : qi == 1 ? rmin1 : qi == 2 ? rmin2 : rmin3;
        v = fminf(v, __shfl_xor(v, 32));
        if (lane < 32) {
            int gi = qbase + qi * 32 + lane;
            float d2 = fmaxf(v + p2s[gi], 0.f);   // clamp keeps uint-bit order valid
            atomicMin(&minsq[gi], __float_as_uint(d2));
        }
    }
}

// Fallback (ws too small / unexpected shape): direct f32 path, targets from global.
__global__ __launch_bounds__(THREADS) void nn_fallback_kernel(
    const float* __restrict__ pred, const float* __restrict__ gt,
    unsigned int* __restrict__ minsq, int N, int B, int nQC, int nTC, int blocksPerDir)
{
    int blk = blockIdx.x;
    int dir = blk / blocksPerDir;
    blk -= dir * blocksPerDir;
    int tc = blk % nTC;
    int qc = (blk / nTC) % nQC;
    int b  = blk / (nTC * nQC);
    const float* q = (dir ? gt : pred) + (size_t)b * 3 * N;
    const float* t = (dir ? pred : gt) + (size_t)b * 3 * N + tc * 256;
    float px[4], py[4], pz[4], p2[4], mn[4];
    int q0 = qc * 1024 + threadIdx.x;
    #pragma unroll
    for (int r = 0; r < 4; ++r) {
        int qi = q0 + r * THREADS;
        px[r] = -2.f * q[qi]; py[r] = -2.f * q[N + qi]; pz[r] = -2.f * q[2 * N + qi];
        p2[r] = fmaf(q[qi], q[qi], fmaf(q[N + qi], q[N + qi], q[2 * N + qi] * q[2 * N + qi]));
        mn[r] = 3.0e38f;
    }
    for (int j = 0; j < 256; j += 4) {
        float4 gx4 = *(const float4*)&t[j];
        float4 gy4 = *(const float4*)&t[N + j];
        float4 gz4 = *(const float4*)&t[2 * N + j];
        float g2_0 = fmaf(gx4.x, gx4.x, fmaf(gy4.x, gy4.x, gz4.x * gz4.x));
        float g2_1 = fmaf(gx4.y, gx4.y, fmaf(gy4.y, gy4.y, gz4.y * gz4.y));
        float g2_2 = fmaf(gx4.z, gx4.z, fmaf(gy4.z, gy4.z, gz4.z * gz4.z));
        float g2_3 = fmaf(gx4.w, gx4.w, fmaf(gy4.w, gy4.w, gz4.w * gz4.w));
        #pragma unroll
        for (int r = 0; r < 4; ++r) {
            float d0 = fmaf(gx4.x, px[r], fmaf(gy4.x, py[r], fmaf(gz4.x, pz[r], g2_0)));
            float d1 = fmaf(gx4.y, px[r], fmaf(gy4.y, py[r], fmaf(gz4.y, pz[r], g2_1)));
            float d2 = fmaf(gx4.z, px[r], fmaf(gy4.z, py[r], fmaf(gz4.z, pz[r], g2_2)));
            float d3 = fmaf(gx4.w, px[r], fmaf(gy4.w, py[r], fmaf(gz4.w, pz[r], g2_3)));
            mn[r] = fminf(fminf(d0, d1), mn[r]);
            mn[r] = fminf(fminf(d2, d3), mn[r]);
        }
    }
    unsigned int* mb = minsq + ((size_t)dir * B + b) * N;
    #pragma unroll
    for (int r = 0; r < 4; ++r) {
        float d2 = fmaxf(mn[r] + p2[r], 0.f);
        atomicMin(&mb[q0 + r * THREADS], __float_as_uint(d2));
    }
}

__global__ __launch_bounds__(THREADS) void reduce1_kernel(
    const unsigned int* __restrict__ minsq, float* __restrict__ partials, int total)
{
    __shared__ float sdata[THREADS];
    float s = 0.f;
    for (int i = blockIdx.x * THREADS + threadIdx.x; i < total; i += gridDim.x * THREADS) {
        float v = __uint_as_float(minsq[i]);
        s += sqrtf(v + 1e-8f);
    }
    sdata[threadIdx.x] = s;
    __syncthreads();
    for (int off = THREADS / 2; off > 0; off >>= 1) {
        if (threadIdx.x < off) sdata[threadIdx.x] += sdata[threadIdx.x + off];
        __syncthreads();
    }
    if (threadIdx.x == 0) partials[blockIdx.x] = sdata[0];
}

__global__ __launch_bounds__(64) void reduce2_kernel(
    const float* __restrict__ partials, float* __restrict__ out, float inv)
{
    float s = partials[threadIdx.x];
    #pragma unroll
    for (int off = 32; off > 0; off >>= 1) s += __shfl_down(s, off);
    if (threadIdx.x == 0) out[0] = s * inv;
}

extern "C" void kernel_launch(void* const* d_in, const int* in_sizes, int n_in,
                              void* d_out, int out_size, void* d_ws, size_t ws_size,
                              hipStream_t stream) {
    const float* pred = (const float*)d_in[0];
    const float* gt   = (const float*)d_in[1];
    const int N = 8192;
    const int B = in_sizes[0] / (3 * N);

    unsigned int* minsq = (unsigned int*)d_ws;
    int total = 2 * B * N;
    float* p2s      = (float*)((char*)d_ws + OFF_P2);
    float* partials = (float*)((char*)d_ws + OFF_PART);
    short8* sA      = (short8*)((char*)d_ws + OFF_SA);
    short8* sB      = (short8*)((char*)d_ws + OFF_SB);

    if (ws_size >= (size_t)WS_NEED && B == NB) {
        prep_kernel<<<total / THREADS, THREADS, 0, stream>>>(pred, gt, sA, sB, p2s, minsq, N);
        nn_mfma_kernel<<<1024, THREADS, 0, stream>>>(sA, sB, p2s, minsq, N);
    } else {
        hipMemsetAsync(minsq, 0x7F, (size_t)total * sizeof(unsigned int), stream);
        int nQC = N / 1024, nTC = N / 256;
        int blocksPerDir = B * nQC * nTC;
        nn_fallback_kernel<<<2 * blocksPerDir, THREADS, 0, stream>>>(
            pred, gt, minsq, N, B, nQC, nTC, blocksPerDir);
    }

    reduce1_kernel<<<64, THREADS, 0, stream>>>(minsq, partials, total);
    reduce2_kernel<<<1, 64, 0, stream>>>(partials, (float*)d_out, 1.0f / (B * N));
}

// Round 8
// 41.040 us; speedup vs baseline: 1.6534x; 1.3064x over previous
//
#include <hip/hip_runtime.h>

#define THREADS 256
#define NB 4                 // batches
#define NPTS 8192            // points per cloud
#define NT (NPTS / 32)       // 256 MFMA tiles per (dir,b)

typedef __attribute__((ext_vector_type(8))) short short8;   // 8 bf16 = 4 VGPR
typedef __attribute__((ext_vector_type(16))) float f32x16;  // MFMA 32x32 acc

// ws layout (bytes):
#define OFF_P2    (256 << 10)
#define OFF_PART  (512 << 10)
#define OFF_SA    (1 << 20)   // target frags: 2*4*256*64*16B = 2 MB
#define OFF_SB    (3 << 20)   // query frags: 2 MB
#define WS_NEED   (5 << 20)

__device__ inline unsigned short f2b(float f) {  // f32 -> bf16 RNE (no NaN inputs here)
    unsigned u = __float_as_uint(f);
    return (unsigned short)((u + 0x7FFFu + ((u >> 16) & 1u)) >> 16);
}
__device__ inline float b2f(unsigned short h) {
    return __uint_as_float(((unsigned)h) << 16);
}

// Pack fragment streams in EXACT mfma_32x32x16_bf16 lane order.
// A-operand (targets, rows): lane l -> row = l&31, k-group = l>>5 (8 bf16).
// K slots: [ghx ghy ghz glx gly glz ghx ghy | ghz g2h g2l 0 0 0 0 0]
// B-operand (queries, cols): lane l -> col = l&31, k-group = l>>5.
// K slots: [ahx ahy ahz ahx ahy ahz alx aly | alz 1 1 0 0 0 0 0], a = split(-2p)
// => acc[target][query] = |g|^2 - 2 p.g   (add |p|^2 afterwards)
__global__ __launch_bounds__(THREADS) void prep_kernel(
    const float* __restrict__ pred, const float* __restrict__ gt,
    short8* __restrict__ sA, short8* __restrict__ sB,
    float* __restrict__ p2s, unsigned int* __restrict__ minsq, int N)
{
    int i = blockIdx.x * THREADS + threadIdx.x;   // [0, 2*NB*N)
    int dir = i / (NB * N);
    int rem = i - dir * NB * N;
    int b = rem / N, idx = rem - b * N;
    const float* q = (dir ? gt : pred) + (size_t)b * 3 * N;  // queries this dir
    const float* t = (dir ? pred : gt) + (size_t)b * 3 * N;  // targets this dir

    size_t ebase = ((size_t)(dir * NB + b)) * NT * 64;
    int tile = idx >> 5, c = idx & 31;

    // target fragment
    float gx = t[idx], gy = t[N + idx], gz = t[2 * N + idx];
    unsigned short ghx = f2b(gx), ghy = f2b(gy), ghz = f2b(gz);
    unsigned short glx = f2b(gx - b2f(ghx)), gly = f2b(gy - b2f(ghy)), glz = f2b(gz - b2f(ghz));
    float g2 = fmaf(gx, gx, fmaf(gy, gy, gz * gz));
    unsigned short g2h = f2b(g2), g2l = f2b(g2 - b2f(g2h));
    short8 ta0, ta1;
    ta0[0]=(short)ghx; ta0[1]=(short)ghy; ta0[2]=(short)ghz; ta0[3]=(short)glx;
    ta0[4]=(short)gly; ta0[5]=(short)glz; ta0[6]=(short)ghx; ta0[7]=(short)ghy;
    ta1[0]=(short)ghz; ta1[1]=(short)g2h; ta1[2]=(short)g2l; ta1[3]=0;
    ta1[4]=0; ta1[5]=0; ta1[6]=0; ta1[7]=0;
    sA[ebase + (size_t)tile * 64 + c]      = ta0;
    sA[ebase + (size_t)tile * 64 + 32 + c] = ta1;

    // query fragment: split of (-2p)
    float px = q[idx], py = q[N + idx], pz = q[2 * N + idx];
    float ax = -2.f * px, ay = -2.f * py, az = -2.f * pz;
    unsigned short ahx = f2b(ax), ahy = f2b(ay), ahz = f2b(az);
    unsigned short alx = f2b(ax - b2f(ahx)), aly = f2b(ay - b2f(ahy)), alz = f2b(az - b2f(ahz));
    const short ONE = (short)0x3F80;
    short8 qb0, qb1;
    qb0[0]=(short)ahx; qb0[1]=(short)ahy; qb0[2]=(short)ahz; qb0[3]=(short)ahx;
    qb0[4]=(short)ahy; qb0[5]=(short)ahz; qb0[6]=(short)alx; qb0[7]=(short)aly;
    qb1[0]=(short)alz; qb1[1]=ONE; qb1[2]=ONE; qb1[3]=0;
    qb1[4]=0; qb1[5]=0; qb1[6]=0; qb1[7]=0;
    sB[ebase + (size_t)tile * 64 + c]      = qb0;
    sB[ebase + (size_t)tile * 64 + 32 + c] = qb1;

    p2s[i] = fmaf(px, px, fmaf(py, py, pz * pz));
    minsq[i] = 0x7F800000u;   // +inf bits
}

#define MFMA(a, b, c) __builtin_amdgcn_mfma_f32_32x32x16_bf16(a, b, c, 0, 0, 0)

// wave = (dir, b, qg, jc): 4 query tiles (128 queries) x 32 target tiles.
// Running min kept VECTORIZED (f32x16 per query tile) -> no serial dep chain;
// horizontal reduction deferred to epilogue.
__global__ __launch_bounds__(THREADS) void nn_mfma_kernel(
    const short8* __restrict__ sA, const short8* __restrict__ sB,
    const float* __restrict__ p2s, unsigned int* __restrict__ minsq, int N)
{
    int w = blockIdx.x * 4 + (threadIdx.x >> 6);   // [0, 4096)
    int lane = threadIdx.x & 63;
    int dir = w >> 11;
    int b   = (w >> 9) & 3;
    int qg  = (w >> 3) & 63;
    int jc  = w & 7;

    size_t ebase = ((size_t)(dir * NB + b)) * NT * 64;
    const short8* A  = sA + ebase;
    const short8* Bq = sB + ebase;

    short8 bq0 = Bq[(size_t)(qg * 4 + 0) * 64 + lane];
    short8 bq1 = Bq[(size_t)(qg * 4 + 1) * 64 + lane];
    short8 bq2 = Bq[(size_t)(qg * 4 + 2) * 64 + lane];
    short8 bq3 = Bq[(size_t)(qg * 4 + 3) * 64 + lane];

    f32x16 z;
    #pragma unroll
    for (int i = 0; i < 16; ++i) z[i] = 0.f;

    f32x16 vm0, vm1, vm2, vm3;
    #pragma unroll
    for (int i = 0; i < 16; ++i) { vm0[i] = 3.0e38f; vm1[i] = 3.0e38f; vm2[i] = 3.0e38f; vm3[i] = 3.0e38f; }

    const short8* ap = A + (size_t)(jc * 32) * 64 + lane;
    for (int t = 0; t < 32; t += 2) {
        short8 a0 = ap[0];
        short8 a1 = ap[64];
        ap += 128;
        {
            f32x16 c0 = MFMA(a0, bq0, z), c1 = MFMA(a1, bq0, z);
            #pragma unroll
            for (int i = 0; i < 16; ++i) vm0[i] = fminf(vm0[i], fminf(c0[i], c1[i]));
        }
        {
            f32x16 c0 = MFMA(a0, bq1, z), c1 = MFMA(a1, bq1, z);
            #pragma unroll
            for (int i = 0; i < 16; ++i) vm1[i] = fminf(vm1[i], fminf(c0[i], c1[i]));
        }
        {
            f32x16 c0 = MFMA(a0, bq2, z), c1 = MFMA(a1, bq2, z);
            #pragma unroll
            for (int i = 0; i < 16; ++i) vm2[i] = fminf(vm2[i], fminf(c0[i], c1[i]));
        }
        {
            f32x16 c0 = MFMA(a0, bq3, z), c1 = MFMA(a1, bq3, z);
            #pragma unroll
            for (int i = 0; i < 16; ++i) vm3[i] = fminf(vm3[i], fminf(c0[i], c1[i]));
        }
    }

    // Epilogue: horizontal min over 16 regs (tree), then xor-32 merge.
    int qbase = (dir * NB + b) * N + qg * 128;
    #pragma unroll
    for (int qi = 0; qi < 4; ++qi) {
        f32x16 vv = qi == 0 ? vm0 : qi == 1 ? vm1 : qi == 2 ? vm2 : vm3;
        float m0 = fminf(fminf(vv[0], vv[1]), fminf(vv[2], vv[3]));
        float m1 = fminf(fminf(vv[4], vv[5]), fminf(vv[6], vv[7]));
        float m2 = fminf(fminf(vv[8], vv[9]), fminf(vv[10], vv[11]));
        float m3 = fminf(fminf(vv[12], vv[13]), fminf(vv[14], vv[15]));
        float v = fminf(fminf(m0, m1), fminf(m2, m3));
        v = fminf(v, __shfl_xor(v, 32));
        if (lane < 32) {
            int gi = qbase + qi * 32 + lane;
            float d2 = fmaxf(v + p2s[gi], 0.f);   // clamp keeps uint-bit order valid
            atomicMin(&minsq[gi], __float_as_uint(d2));
        }
    }
}

// Fallback (ws too small / unexpected shape): direct f32 path, targets from global.
__global__ __launch_bounds__(THREADS) void nn_fallback_kernel(
    const float* __restrict__ pred, const float* __restrict__ gt,
    unsigned int* __restrict__ minsq, int N, int B, int nQC, int nTC, int blocksPerDir)
{
    int blk = blockIdx.x;
    int dir = blk / blocksPerDir;
    blk -= dir * blocksPerDir;
    int tc = blk % nTC;
    int qc = (blk / nTC) % nQC;
    int b  = blk / (nTC * nQC);
    const float* q = (dir ? gt : pred) + (size_t)b * 3 * N;
    const float* t = (dir ? pred : gt) + (size_t)b * 3 * N + tc * 256;
    float px[4], py[4], pz[4], p2[4], mn[4];
    int q0 = qc * 1024 + threadIdx.x;
    #pragma unroll
    for (int r = 0; r < 4; ++r) {
        int qi = q0 + r * THREADS;
        px[r] = -2.f * q[qi]; py[r] = -2.f * q[N + qi]; pz[r] = -2.f * q[2 * N + qi];
        p2[r] = fmaf(q[qi], q[qi], fmaf(q[N + qi], q[N + qi], q[2 * N + qi] * q[2 * N + qi]));
        mn[r] = 3.0e38f;
    }
    for (int j = 0; j < 256; j += 4) {
        float4 gx4 = *(const float4*)&t[j];
        float4 gy4 = *(const float4*)&t[N + j];
        float4 gz4 = *(const float4*)&t[2 * N + j];
        float g2_0 = fmaf(gx4.x, gx4.x, fmaf(gy4.x, gy4.x, gz4.x * gz4.x));
        float g2_1 = fmaf(gx4.y, gx4.y, fmaf(gy4.y, gy4.y, gz4.y * gz4.y));
        float g2_2 = fmaf(gx4.z, gx4.z, fmaf(gy4.z, gy4.z, gz4.z * gz4.z));
        float g2_3 = fmaf(gx4.w, gx4.w, fmaf(gy4.w, gy4.w, gz4.w * gz4.w));
        #pragma unroll
        for (int r = 0; r < 4; ++r) {
            float d0 = fmaf(gx4.x, px[r], fmaf(gy4.x, py[r], fmaf(gz4.x, pz[r], g2_0)));
            float d1 = fmaf(gx4.y, px[r], fmaf(gy4.y, py[r], fmaf(gz4.y, pz[r], g2_1)));
            float d2 = fmaf(gx4.z, px[r], fmaf(gy4.z, py[r], fmaf(gz4.z, pz[r], g2_2)));
            float d3 = fmaf(gx4.w, px[r], fmaf(gy4.w, py[r], fmaf(gz4.w, pz[r], g2_3)));
            mn[r] = fminf(fminf(d0, d1), mn[r]);
            mn[r] = fminf(fminf(d2, d3), mn[r]);
        }
    }
    unsigned int* mb = minsq + ((size_t)dir * B + b) * N;
    #pragma unroll
    for (int r = 0; r < 4; ++r) {
        float d2 = fmaxf(mn[r] + p2[r], 0.f);
        atomicMin(&mb[q0 + r * THREADS], __float_as_uint(d2));
    }
}

__global__ __launch_bounds__(THREADS) void reduce1_kernel(
    const unsigned int* __restrict__ minsq, float* __restrict__ partials, int total)
{
    __shared__ float sdata[THREADS];
    float s = 0.f;
    for (int i = blockIdx.x * THREADS + threadIdx.x; i < total; i += gridDim.x * THREADS) {
        float v = __uint_as_float(minsq[i]);
        s += sqrtf(v + 1e-8f);
    }
    sdata[threadIdx.x] = s;
    __syncthreads();
    for (int off = THREADS / 2; off > 0; off >>= 1) {
        if (threadIdx.x < off) sdata[threadIdx.x] += sdata[threadIdx.x + off];
        __syncthreads();
    }
    if (threadIdx.x == 0) partials[blockIdx.x] = sdata[0];
}

__global__ __launch_bounds__(64) void reduce2_kernel(
    const float* __restrict__ partials, float* __restrict__ out, float inv)
{
    float s = partials[threadIdx.x];
    #pragma unroll
    for (int off = 32; off > 0; off >>= 1) s += __shfl_down(s, off);
    if (threadIdx.x == 0) out[0] = s * inv;
}

extern "C" void kernel_launch(void* const* d_in, const int* in_sizes, int n_in,
                              void* d_out, int out_size, void* d_ws, size_t ws_size,
                              hipStream_t stream) {
    const float* pred = (const float*)d_in[0];
    const float* gt   = (const float*)d_in[1];
    const int N = 8192;
    const int B = in_sizes[0] / (3 * N);

    unsigned int* minsq = (unsigned int*)d_ws;
    int total = 2 * B * N;
    float* p2s      = (float*)((char*)d_ws + OFF_P2);
    float* partials = (float*)((char*)d_ws + OFF_PART);
    short8* sA      = (short8*)((char*)d_ws + OFF_SA);
    short8* sB      = (short8*)((char*)d_ws + OFF_SB);

    if (ws_size >= (size_t)WS_NEED && B == NB) {
        prep_kernel<<<total / THREADS, THREADS, 0, stream>>>(pred, gt, sA, sB, p2s, minsq, N);
        nn_mfma_kernel<<<1024, THREADS, 0, stream>>>(sA, sB, p2s, minsq, N);
    } else {
        hipMemsetAsync(minsq, 0x7F, (size_t)total * sizeof(unsigned int), stream);
        int nQC = N / 1024, nTC = N / 256;
        int blocksPerDir = B * nQC * nTC;
        nn_fallback_kernel<<<2 * blocksPerDir, THREADS, 0, stream>>>(
            pred, gt, minsq, N, B, nQC, nTC, blocksPerDir);
    }

    reduce1_kernel<<<64, THREADS, 0, stream>>>(minsq, partials, total);
    reduce2_kernel<<<1, 64, 0, stream>>>(partials, (float*)d_out, 1.0f / (B * N));
}

// Round 9
// 34.910 us; speedup vs baseline: 1.9438x; 1.1756x over previous
//
#include <hip/hip_runtime.h>

#define THREADS 256
#define NB 4                 // batches
#define NPTS 8192            // points per cloud
#define NT (NPTS / 32)       // 256 MFMA tiles per (dir,b)

typedef __attribute__((ext_vector_type(8))) short short8;   // 8 bf16 = 4 VGPR
typedef __attribute__((ext_vector_type(16))) float f32x16;  // MFMA 32x32 acc

// ws layout (bytes):
#define OFF_P2    (256 << 10)
#define OFF_PART  (512 << 10)
#define OFF_SA    (1 << 20)   // target frags: 2*4*256*64*16B = 2 MB
#define OFF_SB    (3 << 20)   // query frags: 2 MB
#define WS_NEED   (5 << 20)

__device__ inline unsigned short f2b(float f) {  // f32 -> bf16 RNE (no NaN inputs here)
    unsigned u = __float_as_uint(f);
    return (unsigned short)((u + 0x7FFFu + ((u >> 16) & 1u)) >> 16);
}
__device__ inline float b2f(unsigned short h) {
    return __uint_as_float(((unsigned)h) << 16);
}

// Pack fragment streams in EXACT mfma_32x32x16_bf16 lane order.
// A-operand (targets, rows): lane l -> row = l&31, k-group = l>>5 (8 bf16).
// K slots: [ghx ghy ghz glx gly glz ghx ghy | ghz g2h g2l 0 0 0 0 0]
// B-operand (queries, cols): lane l -> col = l&31, k-group = l>>5.
// K slots: [ahx ahy ahz ahx ahy ahz alx aly | alz 1 1 0 0 0 0 0], a = split(-2p)
// => acc[target][query] = |g|^2 - 2 p.g   (add |p|^2 afterwards)
__global__ __launch_bounds__(THREADS) void prep_kernel(
    const float* __restrict__ pred, const float* __restrict__ gt,
    short8* __restrict__ sA, short8* __restrict__ sB,
    float* __restrict__ p2s, unsigned int* __restrict__ minsq, int N)
{
    int i = blockIdx.x * THREADS + threadIdx.x;   // [0, 2*NB*N)
    int dir = i / (NB * N);
    int rem = i - dir * NB * N;
    int b = rem / N, idx = rem - b * N;
    const float* q = (dir ? gt : pred) + (size_t)b * 3 * N;  // queries this dir
    const float* t = (dir ? pred : gt) + (size_t)b * 3 * N;  // targets this dir

    size_t ebase = ((size_t)(dir * NB + b)) * NT * 64;
    int tile = idx >> 5, c = idx & 31;

    // target fragment
    float gx = t[idx], gy = t[N + idx], gz = t[2 * N + idx];
    unsigned short ghx = f2b(gx), ghy = f2b(gy), ghz = f2b(gz);
    unsigned short glx = f2b(gx - b2f(ghx)), gly = f2b(gy - b2f(ghy)), glz = f2b(gz - b2f(ghz));
    float g2 = fmaf(gx, gx, fmaf(gy, gy, gz * gz));
    unsigned short g2h = f2b(g2), g2l = f2b(g2 - b2f(g2h));
    short8 ta0, ta1;
    ta0[0]=(short)ghx; ta0[1]=(short)ghy; ta0[2]=(short)ghz; ta0[3]=(short)glx;
    ta0[4]=(short)gly; ta0[5]=(short)glz; ta0[6]=(short)ghx; ta0[7]=(short)ghy;
    ta1[0]=(short)ghz; ta1[1]=(short)g2h; ta1[2]=(short)g2l; ta1[3]=0;
    ta1[4]=0; ta1[5]=0; ta1[6]=0; ta1[7]=0;
    sA[ebase + (size_t)tile * 64 + c]      = ta0;
    sA[ebase + (size_t)tile * 64 + 32 + c] = ta1;

    // query fragment: split of (-2p)
    float px = q[idx], py = q[N + idx], pz = q[2 * N + idx];
    float ax = -2.f * px, ay = -2.f * py, az = -2.f * pz;
    unsigned short ahx = f2b(ax), ahy = f2b(ay), ahz = f2b(az);
    unsigned short alx = f2b(ax - b2f(ahx)), aly = f2b(ay - b2f(ahy)), alz = f2b(az - b2f(ahz));
    const short ONE = (short)0x3F80;
    short8 qb0, qb1;
    qb0[0]=(short)ahx; qb0[1]=(short)ahy; qb0[2]=(short)ahz; qb0[3]=(short)ahx;
    qb0[4]=(short)ahy; qb0[5]=(short)ahz; qb0[6]=(short)alx; qb0[7]=(short)aly;
    qb1[0]=(short)alz; qb1[1]=ONE; qb1[2]=ONE; qb1[3]=0;
    qb1[4]=0; qb1[5]=0; qb1[6]=0; qb1[7]=0;
    sB[ebase + (size_t)tile * 64 + c]      = qb0;
    sB[ebase + (size_t)tile * 64 + 32 + c] = qb1;

    p2s[i] = fmaf(px, px, fmaf(py, py, pz * pz));
    minsq[i] = 0x7F800000u;   // +inf bits
}

#define MFMA(a, b, c) __builtin_amdgcn_mfma_f32_32x32x16_bf16(a, b, c, 0, 0, 0)

// wave = (dir, b, qp, jc): 2 query tiles (64 queries) x 64 target tiles.
// __launch_bounds__(256,4): cap at 128 VGPRs so the unified-file allocator
// keeps MFMA accs in VGPRs (no v_accvgpr_read/write around the min3s).
__global__ __launch_bounds__(THREADS, 4) void nn_mfma_kernel(
    const short8* __restrict__ sA, const short8* __restrict__ sB,
    const float* __restrict__ p2s, unsigned int* __restrict__ minsq, int N)
{
    int w = blockIdx.x * 4 + (threadIdx.x >> 6);   // [0, 4096)
    int lane = threadIdx.x & 63;
    int dir = w >> 11;
    int b   = (w >> 9) & 3;
    int qp  = (w >> 2) & 127;   // query tile pair
    int jc  = w & 3;            // 64-tile target chunk

    size_t ebase = ((size_t)(dir * NB + b)) * NT * 64;
    const short8* A  = sA + ebase;
    const short8* Bq = sB + ebase;

    short8 bq0 = Bq[(size_t)(qp * 2 + 0) * 64 + lane];
    short8 bq1 = Bq[(size_t)(qp * 2 + 1) * 64 + lane];

    f32x16 z;
    #pragma unroll
    for (int i = 0; i < 16; ++i) z[i] = 0.f;

    f32x16 vm0, vm1;
    #pragma unroll
    for (int i = 0; i < 16; ++i) { vm0[i] = 3.0e38f; vm1[i] = 3.0e38f; }

    const short8* ap = A + (size_t)(jc * 64) * 64 + lane;
    for (int t = 0; t < 64; t += 2) {
        short8 a0 = ap[0];
        short8 a1 = ap[64];
        ap += 128;
        {
            f32x16 c0 = MFMA(a0, bq0, z), c1 = MFMA(a1, bq0, z);
            #pragma unroll
            for (int i = 0; i < 16; ++i) vm0[i] = fminf(vm0[i], fminf(c0[i], c1[i]));
        }
        {
            f32x16 c0 = MFMA(a0, bq1, z), c1 = MFMA(a1, bq1, z);
            #pragma unroll
            for (int i = 0; i < 16; ++i) vm1[i] = fminf(vm1[i], fminf(c0[i], c1[i]));
        }
    }

    // Epilogue: horizontal min over 16 regs (tree), then xor-32 merge.
    int qbase = (dir * NB + b) * N + qp * 64;
    #pragma unroll
    for (int qi = 0; qi < 2; ++qi) {
        f32x16 vv = qi == 0 ? vm0 : vm1;
        float m0 = fminf(fminf(vv[0], vv[1]), fminf(vv[2], vv[3]));
        float m1 = fminf(fminf(vv[4], vv[5]), fminf(vv[6], vv[7]));
        float m2 = fminf(fminf(vv[8], vv[9]), fminf(vv[10], vv[11]));
        float m3 = fminf(fminf(vv[12], vv[13]), fminf(vv[14], vv[15]));
        float v = fminf(fminf(m0, m1), fminf(m2, m3));
        v = fminf(v, __shfl_xor(v, 32));
        if (lane < 32) {
            int gi = qbase + qi * 32 + lane;
            float d2 = fmaxf(v + p2s[gi], 0.f);   // clamp keeps uint-bit order valid
            atomicMin(&minsq[gi], __float_as_uint(d2));
        }
    }
}

// Fallback (ws too small / unexpected shape): direct f32 path, targets from global.
__global__ __launch_bounds__(THREADS) void nn_fallback_kernel(
    const float* __restrict__ pred, const float* __restrict__ gt,
    unsigned int* __restrict__ minsq, int N, int B, int nQC, int nTC, int blocksPerDir)
{
    int blk = blockIdx.x;
    int dir = blk / blocksPerDir;
    blk -= dir * blocksPerDir;
    int tc = blk % nTC;
    int qc = (blk / nTC) % nQC;
    int b  = blk / (nTC * nQC);
    const float* q = (dir ? gt : pred) + (size_t)b * 3 * N;
    const float* t = (dir ? pred : gt) + (size_t)b * 3 * N + tc * 256;
    float px[4], py[4], pz[4], p2[4], mn[4];
    int q0 = qc * 1024 + threadIdx.x;
    #pragma unroll
    for (int r = 0; r < 4; ++r) {
        int qi = q0 + r * THREADS;
        px[r] = -2.f * q[qi]; py[r] = -2.f * q[N + qi]; pz[r] = -2.f * q[2 * N + qi];
        p2[r] = fmaf(q[qi], q[qi], fmaf(q[N + qi], q[N + qi], q[2 * N + qi] * q[2 * N + qi]));
        mn[r] = 3.0e38f;
    }
    for (int j = 0; j < 256; j += 4) {
        float4 gx4 = *(const float4*)&t[j];
        float4 gy4 = *(const float4*)&t[N + j];
        float4 gz4 = *(const float4*)&t[2 * N + j];
        float g2_0 = fmaf(gx4.x, gx4.x, fmaf(gy4.x, gy4.x, gz4.x * gz4.x));
        float g2_1 = fmaf(gx4.y, gx4.y, fmaf(gy4.y, gy4.y, gz4.y * gz4.y));
        float g2_2 = fmaf(gx4.z, gx4.z, fmaf(gy4.z, gy4.z, gz4.z * gz4.z));
        float g2_3 = fmaf(gx4.w, gx4.w, fmaf(gy4.w, gy4.w, gz4.w * gz4.w));
        #pragma unroll
        for (int r = 0; r < 4; ++r) {
            float d0 = fmaf(gx4.x, px[r], fmaf(gy4.x, py[r], fmaf(gz4.x, pz[r], g2_0)));
            float d1 = fmaf(gx4.y, px[r], fmaf(gy4.y, py[r], fmaf(gz4.y, pz[r], g2_1)));
            float d2 = fmaf(gx4.z, px[r], fmaf(gy4.z, py[r], fmaf(gz4.z, pz[r], g2_2)));
            float d3 = fmaf(gx4.w, px[r], fmaf(gy4.w, py[r], fmaf(gz4.w, pz[r], g2_3)));
            mn[r] = fminf(fminf(d0, d1), mn[r]);
            mn[r] = fminf(fminf(d2, d3), mn[r]);
        }
    }
    unsigned int* mb = minsq + ((size_t)dir * B + b) * N;
    #pragma unroll
    for (int r = 0; r < 4; ++r) {
        float d2 = fmaxf(mn[r] + p2[r], 0.f);
        atomicMin(&mb[q0 + r * THREADS], __float_as_uint(d2));
    }
}

__global__ __launch_bounds__(THREADS) void reduce1_kernel(
    const unsigned int* __restrict__ minsq, float* __restrict__ partials, int total)
{
    __shared__ float sdata[THREADS];
    float s = 0.f;
    for (int i = blockIdx.x * THREADS + threadIdx.x; i < total; i += gridDim.x * THREADS) {
        float v = __uint_as_float(minsq[i]);
        s += sqrtf(v + 1e-8f);
    }
    sdata[threadIdx.x] = s;
    __syncthreads();
    for (int off = THREADS / 2; off > 0; off >>= 1) {
        if (threadIdx.x < off) sdata[threadIdx.x] += sdata[threadIdx.x + off];
        __syncthreads();
    }
    if (threadIdx.x == 0) partials[blockIdx.x] = sdata[0];
}

__global__ __launch_bounds__(64) void reduce2_kernel(
    const float* __restrict__ partials, float* __restrict__ out, float inv)
{
    float s = partials[threadIdx.x];
    #pragma unroll
    for (int off = 32; off > 0; off >>= 1) s += __shfl_down(s, off);
    if (threadIdx.x == 0) out[0] = s * inv;
}

extern "C" void kernel_launch(void* const* d_in, const int* in_sizes, int n_in,
                              void* d_out, int out_size, void* d_ws, size_t ws_size,
                              hipStream_t stream) {
    const float* pred = (const float*)d_in[0];
    const float* gt   = (const float*)d_in[1];
    const int N = 8192;
    const int B = in_sizes[0] / (3 * N);

    unsigned int* minsq = (unsigned int*)d_ws;
    int total = 2 * B * N;
    float* p2s      = (float*)((char*)d_ws + OFF_P2);
    float* partials = (float*)((char*)d_ws + OFF_PART);
    short8* sA      = (short8*)((char*)d_ws + OFF_SA);
    short8* sB      = (short8*)((char*)d_ws + OFF_SB);

    if (ws_size >= (size_t)WS_NEED && B == NB) {
        prep_kernel<<<total / THREADS, THREADS, 0, stream>>>(pred, gt, sA, sB, p2s, minsq, N);
        nn_mfma_kernel<<<1024, THREADS, 0, stream>>>(sA, sB, p2s, minsq, N);
    } else {
        hipMemsetAsync(minsq, 0x7F, (size_t)total * sizeof(unsigned int), stream);
        int nQC = N / 1024, nTC = N / 256;
        int blocksPerDir = B * nQC * nTC;
        nn_fallback_kernel<<<2 * blocksPerDir, THREADS, 0, stream>>>(
            pred, gt, minsq, N, B, nQC, nTC, blocksPerDir);
    }

    reduce1_kernel<<<64, THREADS, 0, stream>>>(minsq, partials, total);
    reduce2_kernel<<<1, 64, 0, stream>>>(partials, (float*)d_out, 1.0f / (B * N));
}

// Round 10
// 33.537 us; speedup vs baseline: 2.0233x; 1.0409x over previous
//
#include <hip/hip_runtime.h>

#define THREADS 256
#define NB 4                 // batches
#define NPTS 8192            // points per cloud
#define NT (NPTS / 32)       // 256 MFMA tiles per (dir,b)

typedef __attribute__((ext_vector_type(8))) short short8;   // 8 bf16 = 4 VGPR
typedef __attribute__((ext_vector_type(16))) float f32x16;  // MFMA 32x32 acc

// ws layout (bytes):
#define OFF_P2    (256 << 10)
#define OFF_PART  (512 << 10)
#define OFF_SA    (1 << 20)   // target frags: 2*4*256*64*16B = 2 MB
#define OFF_SB    (3 << 20)   // query frags: 2 MB
#define WS_NEED   (5 << 20)

__device__ inline unsigned short f2b(float f) {  // f32 -> bf16 RNE (no NaN inputs here)
    unsigned u = __float_as_uint(f);
    return (unsigned short)((u + 0x7FFFu + ((u >> 16) & 1u)) >> 16);
}
__device__ inline float b2f(unsigned short h) {
    return __uint_as_float(((unsigned)h) << 16);
}

// Pack fragment streams in EXACT mfma_32x32x16_bf16 lane order.
// A-operand (targets, rows): lane l -> row = l&31, k-group = l>>5 (8 bf16).
// K slots: [ghx ghy ghz glx gly glz ghx ghy | ghz g2h g2l 0 0 0 0 0]
// B-operand (queries, cols): lane l -> col = l&31, k-group = l>>5.
// K slots: [ahx ahy ahz ahx ahy ahz alx aly | alz 1 1 0 0 0 0 0], a = split(-2p)
// => acc[target][query] = |g|^2 - 2 p.g   (add |p|^2 afterwards)
__global__ __launch_bounds__(THREADS) void prep_kernel(
    const float* __restrict__ pred, const float* __restrict__ gt,
    short8* __restrict__ sA, short8* __restrict__ sB,
    float* __restrict__ p2s, unsigned int* __restrict__ minsq, int N)
{
    int i = blockIdx.x * THREADS + threadIdx.x;   // [0, 2*NB*N)
    int dir = i / (NB * N);
    int rem = i - dir * NB * N;
    int b = rem / N, idx = rem - b * N;
    const float* q = (dir ? gt : pred) + (size_t)b * 3 * N;  // queries this dir
    const float* t = (dir ? pred : gt) + (size_t)b * 3 * N;  // targets this dir

    size_t ebase = ((size_t)(dir * NB + b)) * NT * 64;
    int tile = idx >> 5, c = idx & 31;

    // target fragment
    float gx = t[idx], gy = t[N + idx], gz = t[2 * N + idx];
    unsigned short ghx = f2b(gx), ghy = f2b(gy), ghz = f2b(gz);
    unsigned short glx = f2b(gx - b2f(ghx)), gly = f2b(gy - b2f(ghy)), glz = f2b(gz - b2f(ghz));
    float g2 = fmaf(gx, gx, fmaf(gy, gy, gz * gz));
    unsigned short g2h = f2b(g2), g2l = f2b(g2 - b2f(g2h));
    short8 ta0, ta1;
    ta0[0]=(short)ghx; ta0[1]=(short)ghy; ta0[2]=(short)ghz; ta0[3]=(short)glx;
    ta0[4]=(short)gly; ta0[5]=(short)glz; ta0[6]=(short)ghx; ta0[7]=(short)ghy;
    ta1[0]=(short)ghz; ta1[1]=(short)g2h; ta1[2]=(short)g2l; ta1[3]=0;
    ta1[4]=0; ta1[5]=0; ta1[6]=0; ta1[7]=0;
    sA[ebase + (size_t)tile * 64 + c]      = ta0;
    sA[ebase + (size_t)tile * 64 + 32 + c] = ta1;

    // query fragment: split of (-2p)
    float px = q[idx], py = q[N + idx], pz = q[2 * N + idx];
    float ax = -2.f * px, ay = -2.f * py, az = -2.f * pz;
    unsigned short ahx = f2b(ax), ahy = f2b(ay), ahz = f2b(az);
    unsigned short alx = f2b(ax - b2f(ahx)), aly = f2b(ay - b2f(ahy)), alz = f2b(az - b2f(ahz));
    const short ONE = (short)0x3F80;
    short8 qb0, qb1;
    qb0[0]=(short)ahx; qb0[1]=(short)ahy; qb0[2]=(short)ahz; qb0[3]=(short)ahx;
    qb0[4]=(short)ahy; qb0[5]=(short)ahz; qb0[6]=(short)alx; qb0[7]=(short)aly;
    qb1[0]=(short)alz; qb1[1]=ONE; qb1[2]=ONE; qb1[3]=0;
    qb1[4]=0; qb1[5]=0; qb1[6]=0; qb1[7]=0;
    sB[ebase + (size_t)tile * 64 + c]      = qb0;
    sB[ebase + (size_t)tile * 64 + 32 + c] = qb1;

    p2s[i] = fmaf(px, px, fmaf(py, py, pz * pz));
    minsq[i] = 0x7F800000u;   // +inf bits
}

#define MFMA(a, b, c) __builtin_amdgcn_mfma_f32_32x32x16_bf16(a, b, c, 0, 0, 0)

// wave = (dir, b, jc, qp): 2 query tiles (64 queries) x 64 target tiles.
// qp in the LOW bits -> a block's 4 waves share the same jc chunk (L2 line
// sharing on the A-stream). A-loads software-pipelined 2 deep to hide L2 lat.
__global__ __launch_bounds__(THREADS, 4) void nn_mfma_kernel(
    const short8* __restrict__ sA, const short8* __restrict__ sB,
    const float* __restrict__ p2s, unsigned int* __restrict__ minsq, int N)
{
    int w = blockIdx.x * 4 + (threadIdx.x >> 6);   // [0, 4096)
    int lane = threadIdx.x & 63;
    int dir = w >> 11;
    int b   = (w >> 9) & 3;
    int jc  = (w >> 7) & 3;     // 64-tile target chunk (shared within block)
    int qp  = w & 127;          // query tile pair

    size_t ebase = ((size_t)(dir * NB + b)) * NT * 64;
    const short8* A  = sA + ebase;
    const short8* Bq = sB + ebase;

    short8 bq0 = Bq[(size_t)(qp * 2 + 0) * 64 + lane];
    short8 bq1 = Bq[(size_t)(qp * 2 + 1) * 64 + lane];

    f32x16 z;
    #pragma unroll
    for (int i = 0; i < 16; ++i) z[i] = 0.f;

    f32x16 vm0, vm1;
    #pragma unroll
    for (int i = 0; i < 16; ++i) { vm0[i] = 3.0e38f; vm1[i] = 3.0e38f; }

    const short8* chunk = A + (size_t)(jc * 64) * 64 + lane;
    // 2-deep software pipeline on the A tile-pair stream.
    short8 a0  = chunk[0],   a1  = chunk[64];
    short8 na0 = chunk[128], na1 = chunk[192];
    for (int t = 0; t < 64; t += 2) {
        int tp = (t + 4) & 63;              // prefetch 2 pairs ahead (wraps; unused tail)
        short8 pa0 = chunk[(size_t)tp * 64];
        short8 pa1 = chunk[(size_t)(tp + 1) * 64];
        {
            f32x16 c0 = MFMA(a0, bq0, z), c1 = MFMA(a1, bq0, z);
            #pragma unroll
            for (int i = 0; i < 16; ++i) vm0[i] = fminf(vm0[i], fminf(c0[i], c1[i]));
        }
        {
            f32x16 c0 = MFMA(a0, bq1, z), c1 = MFMA(a1, bq1, z);
            #pragma unroll
            for (int i = 0; i < 16; ++i) vm1[i] = fminf(vm1[i], fminf(c0[i], c1[i]));
        }
        a0 = na0; a1 = na1; na0 = pa0; na1 = pa1;
    }

    // Epilogue: horizontal min over 16 regs (tree), then xor-32 merge.
    int qbase = (dir * NB + b) * N + qp * 64;
    #pragma unroll
    for (int qi = 0; qi < 2; ++qi) {
        f32x16 vv = qi == 0 ? vm0 : vm1;
        float m0 = fminf(fminf(vv[0], vv[1]), fminf(vv[2], vv[3]));
        float m1 = fminf(fminf(vv[4], vv[5]), fminf(vv[6], vv[7]));
        float m2 = fminf(fminf(vv[8], vv[9]), fminf(vv[10], vv[11]));
        float m3 = fminf(fminf(vv[12], vv[13]), fminf(vv[14], vv[15]));
        float v = fminf(fminf(m0, m1), fminf(m2, m3));
        v = fminf(v, __shfl_xor(v, 32));
        if (lane < 32) {
            int gi = qbase + qi * 32 + lane;
            float d2 = fmaxf(v + p2s[gi], 0.f);   // clamp keeps uint-bit order valid
            atomicMin(&minsq[gi], __float_as_uint(d2));
        }
    }
}

// Fallback (ws too small / unexpected shape): direct f32 path, targets from global.
__global__ __launch_bounds__(THREADS) void nn_fallback_kernel(
    const float* __restrict__ pred, const float* __restrict__ gt,
    unsigned int* __restrict__ minsq, int N, int B, int nQC, int nTC, int blocksPerDir)
{
    int blk = blockIdx.x;
    int dir = blk / blocksPerDir;
    blk -= dir * blocksPerDir;
    int tc = blk % nTC;
    int qc = (blk / nTC) % nQC;
    int b  = blk / (nTC * nQC);
    const float* q = (dir ? gt : pred) + (size_t)b * 3 * N;
    const float* t = (dir ? pred : gt) + (size_t)b * 3 * N + tc * 256;
    float px[4], py[4], pz[4], p2[4], mn[4];
    int q0 = qc * 1024 + threadIdx.x;
    #pragma unroll
    for (int r = 0; r < 4; ++r) {
        int qi = q0 + r * THREADS;
        px[r] = -2.f * q[qi]; py[r] = -2.f * q[N + qi]; pz[r] = -2.f * q[2 * N + qi];
        p2[r] = fmaf(q[qi], q[qi], fmaf(q[N + qi], q[N + qi], q[2 * N + qi] * q[2 * N + qi]));
        mn[r] = 3.0e38f;
    }
    for (int j = 0; j < 256; j += 4) {
        float4 gx4 = *(const float4*)&t[j];
        float4 gy4 = *(const float4*)&t[N + j];
        float4 gz4 = *(const float4*)&t[2 * N + j];
        float g2_0 = fmaf(gx4.x, gx4.x, fmaf(gy4.x, gy4.x, gz4.x * gz4.x));
        float g2_1 = fmaf(gx4.y, gx4.y, fmaf(gy4.y, gy4.y, gz4.y * gz4.y));
        float g2_2 = fmaf(gx4.z, gx4.z, fmaf(gy4.z, gy4.z, gz4.z * gz4.z));
        float g2_3 = fmaf(gx4.w, gx4.w, fmaf(gy4.w, gy4.w, gz4.w * gz4.w));
        #pragma unroll
        for (int r = 0; r < 4; ++r) {
            float d0 = fmaf(gx4.x, px[r], fmaf(gy4.x, py[r], fmaf(gz4.x, pz[r], g2_0)));
            float d1 = fmaf(gx4.y, px[r], fmaf(gy4.y, py[r], fmaf(gz4.y, pz[r], g2_1)));
            float d2 = fmaf(gx4.z, px[r], fmaf(gy4.z, py[r], fmaf(gz4.z, pz[r], g2_2)));
            float d3 = fmaf(gx4.w, px[r], fmaf(gy4.w, py[r], fmaf(gz4.w, pz[r], g2_3)));
            mn[r] = fminf(fminf(d0, d1), mn[r]);
            mn[r] = fminf(fminf(d2, d3), mn[r]);
        }
    }
    unsigned int* mb = minsq + ((size_t)dir * B + b) * N;
    #pragma unroll
    for (int r = 0; r < 4; ++r) {
        float d2 = fmaxf(mn[r] + p2[r], 0.f);
        atomicMin(&mb[q0 + r * THREADS], __float_as_uint(d2));
    }
}

__global__ __launch_bounds__(THREADS) void reduce1_kernel(
    const unsigned int* __restrict__ minsq, float* __restrict__ partials, int total)
{
    __shared__ float sdata[THREADS];
    float s = 0.f;
    for (int i = blockIdx.x * THREADS + threadIdx.x; i < total; i += gridDim.x * THREADS) {
        float v = __uint_as_float(minsq[i]);
        s += sqrtf(v + 1e-8f);
    }
    sdata[threadIdx.x] = s;
    __syncthreads();
    for (int off = THREADS / 2; off > 0; off >>= 1) {
        if (threadIdx.x < off) sdata[threadIdx.x] += sdata[threadIdx.x + off];
        __syncthreads();
    }
    if (threadIdx.x == 0) partials[blockIdx.x] = sdata[0];
}

__global__ __launch_bounds__(64) void reduce2_kernel(
    const float* __restrict__ partials, float* __restrict__ out, float inv)
{
    float s = partials[threadIdx.x];
    #pragma unroll
    for (int off = 32; off > 0; off >>= 1) s += __shfl_down(s, off);
    if (threadIdx.x == 0) out[0] = s * inv;
}

extern "C" void kernel_launch(void* const* d_in, const int* in_sizes, int n_in,
                              void* d_out, int out_size, void* d_ws, size_t ws_size,
                              hipStream_t stream) {
    const float* pred = (const float*)d_in[0];
    const float* gt   = (const float*)d_in[1];
    const int N = 8192;
    const int B = in_sizes[0] / (3 * N);

    unsigned int* minsq = (unsigned int*)d_ws;
    int total = 2 * B * N;
    float* p2s      = (float*)((char*)d_ws + OFF_P2);
    float* partials = (float*)((char*)d_ws + OFF_PART);
    short8* sA      = (short8*)((char*)d_ws + OFF_SA);
    short8* sB      = (short8*)((char*)d_ws + OFF_SB);

    if (ws_size >= (size_t)WS_NEED && B == NB) {
        prep_kernel<<<total / THREADS, THREADS, 0, stream>>>(pred, gt, sA, sB, p2s, minsq, N);
        nn_mfma_kernel<<<1024, THREADS, 0, stream>>>(sA, sB, p2s, minsq, N);
    } else {
        hipMemsetAsync(minsq, 0x7F, (size_t)total * sizeof(unsigned int), stream);
        int nQC = N / 1024, nTC = N / 256;
        int blocksPerDir = B * nQC * nTC;
        nn_fallback_kernel<<<2 * blocksPerDir, THREADS, 0, stream>>>(
            pred, gt, minsq, N, B, nQC, nTC, blocksPerDir);
    }

    reduce1_kernel<<<64, THREADS, 0, stream>>>(minsq, partials, total);
    reduce2_kernel<<<1, 64, 0, stream>>>(partials, (float*)d_out, 1.0f / (B * N));
}

// Round 11
// 32.624 us; speedup vs baseline: 2.0799x; 1.0280x over previous
//
#include <hip/hip_runtime.h>

#define THREADS 256
#define NB 4                 // batches
#define NPTS 8192            // points per cloud
#define NT (NPTS / 32)       // 256 MFMA tiles per (dir,b)
#define CHT 32               // A-tiles per LDS chunk (32 KB)

typedef __attribute__((ext_vector_type(8))) short short8;   // 8 bf16 = 4 VGPR
typedef __attribute__((ext_vector_type(16))) float f32x16;  // MFMA 32x32 acc

// ws layout (bytes):
#define OFF_P2    (256 << 10)
#define OFF_PART  (512 << 10)
#define OFF_SA    (1 << 20)   // target frags: 2*4*256*64*16B = 2 MB
#define OFF_SB    (3 << 20)   // query frags: 2 MB
#define WS_NEED   (5 << 20)

__device__ inline unsigned short f2b(float f) {  // f32 -> bf16 RNE (no NaN inputs here)
    unsigned u = __float_as_uint(f);
    return (unsigned short)((u + 0x7FFFu + ((u >> 16) & 1u)) >> 16);
}
__device__ inline float b2f(unsigned short h) {
    return __uint_as_float(((unsigned)h) << 16);
}

// Pack fragment streams in EXACT mfma_32x32x16_bf16 lane order.
// A-operand (targets, rows): lane l -> row = l&31, k-group = l>>5 (8 bf16).
// K slots: [ghx ghy ghz glx gly glz ghx ghy | ghz g2h g2l 0 0 0 0 0]
// B-operand (queries, cols): lane l -> col = l&31, k-group = l>>5.
// K slots: [ahx ahy ahz ahx ahy ahz alx aly | alz 1 1 0 0 0 0 0], a = split(-2p)
// => acc[target][query] = |g|^2 - 2 p.g   (add |p|^2 afterwards)
__global__ __launch_bounds__(THREADS) void prep_kernel(
    const float* __restrict__ pred, const float* __restrict__ gt,
    short8* __restrict__ sA, short8* __restrict__ sB,
    float* __restrict__ p2s, unsigned int* __restrict__ minsq, int N)
{
    int i = blockIdx.x * THREADS + threadIdx.x;   // [0, 2*NB*N)
    int dir = i / (NB * N);
    int rem = i - dir * NB * N;
    int b = rem / N, idx = rem - b * N;
    const float* q = (dir ? gt : pred) + (size_t)b * 3 * N;  // queries this dir
    const float* t = (dir ? pred : gt) + (size_t)b * 3 * N;  // targets this dir

    size_t ebase = ((size_t)(dir * NB + b)) * NT * 64;
    int tile = idx >> 5, c = idx & 31;

    // target fragment
    float gx = t[idx], gy = t[N + idx], gz = t[2 * N + idx];
    unsigned short ghx = f2b(gx), ghy = f2b(gy), ghz = f2b(gz);
    unsigned short glx = f2b(gx - b2f(ghx)), gly = f2b(gy - b2f(ghy)), glz = f2b(gz - b2f(ghz));
    float g2 = fmaf(gx, gx, fmaf(gy, gy, gz * gz));
    unsigned short g2h = f2b(g2), g2l = f2b(g2 - b2f(g2h));
    short8 ta0, ta1;
    ta0[0]=(short)ghx; ta0[1]=(short)ghy; ta0[2]=(short)ghz; ta0[3]=(short)glx;
    ta0[4]=(short)gly; ta0[5]=(short)glz; ta0[6]=(short)ghx; ta0[7]=(short)ghy;
    ta1[0]=(short)ghz; ta1[1]=(short)g2h; ta1[2]=(short)g2l; ta1[3]=0;
    ta1[4]=0; ta1[5]=0; ta1[6]=0; ta1[7]=0;
    sA[ebase + (size_t)tile * 64 + c]      = ta0;
    sA[ebase + (size_t)tile * 64 + 32 + c] = ta1;

    // query fragment: split of (-2p)
    float px = q[idx], py = q[N + idx], pz = q[2 * N + idx];
    float ax = -2.f * px, ay = -2.f * py, az = -2.f * pz;
    unsigned short ahx = f2b(ax), ahy = f2b(ay), ahz = f2b(az);
    unsigned short alx = f2b(ax - b2f(ahx)), aly = f2b(ay - b2f(ahy)), alz = f2b(az - b2f(ahz));
    const short ONE = (short)0x3F80;
    short8 qb0, qb1;
    qb0[0]=(short)ahx; qb0[1]=(short)ahy; qb0[2]=(short)ahz; qb0[3]=(short)ahx;
    qb0[4]=(short)ahy; qb0[5]=(short)ahz; qb0[6]=(short)alx; qb0[7]=(short)aly;
    qb1[0]=(short)alz; qb1[1]=ONE; qb1[2]=ONE; qb1[3]=0;
    qb1[4]=0; qb1[5]=0; qb1[6]=0; qb1[7]=0;
    sB[ebase + (size_t)tile * 64 + c]      = qb0;
    sB[ebase + (size_t)tile * 64 + 32 + c] = qb1;

    p2s[i] = fmaf(px, px, fmaf(py, py, pz * pz));
    minsq[i] = 0x7F800000u;   // +inf bits
}

#define MFMA(a, b, c) __builtin_amdgcn_mfma_f32_32x32x16_bf16(a, b, c, 0, 0, 0)

// block = (dir, b, chunk, qpg): stages a 32-tile A-chunk (32 KB) in LDS once;
// its 4 waves each process their own query pair against the whole chunk.
// A L2 traffic drops 4x and ds_read latency replaces L2 latency in the loop.
__global__ __launch_bounds__(THREADS, 4) void nn_mfma_kernel(
    const short8* __restrict__ sA, const short8* __restrict__ sB,
    const float* __restrict__ p2s, unsigned int* __restrict__ minsq, int N)
{
    __shared__ short8 lA[CHT * 64];   // 32 KB

    int wave = threadIdx.x >> 6;
    int lane = threadIdx.x & 63;
    int blk = blockIdx.x;             // [0, 2048)
    int dir   = blk >> 10;
    int b     = (blk >> 8) & 3;
    int chunk = (blk >> 5) & 7;       // 8 chunks of 32 tiles
    int qpg   = blk & 31;             // 32 query-pair groups (x4 waves = 128 pairs)

    size_t ebase = ((size_t)(dir * NB + b)) * NT * 64;
    const short8* Achunk = sA + ebase + (size_t)chunk * CHT * 64;
    const short8* Bq     = sB + ebase;

    // cooperative stage: 2048 entries / 256 threads = 8 each
    #pragma unroll
    for (int k = 0; k < 8; ++k) {
        int e = (wave * 8 + k) * 64 + lane;
        lA[e] = Achunk[e];
    }

    int qp = qpg * 4 + wave;          // this wave's query pair [0,128)
    short8 bq0 = Bq[(size_t)(qp * 2 + 0) * 64 + lane];
    short8 bq1 = Bq[(size_t)(qp * 2 + 1) * 64 + lane];

    f32x16 z;
    #pragma unroll
    for (int i = 0; i < 16; ++i) z[i] = 0.f;

    f32x16 vm0, vm1;
    #pragma unroll
    for (int i = 0; i < 16; ++i) { vm0[i] = 3.0e38f; vm1[i] = 3.0e38f; }

    __syncthreads();

    // 1-deep register pipeline over LDS tile-pairs
    short8 a0 = lA[lane], a1 = lA[64 + lane];
    for (int t = 0; t < CHT; t += 2) {
        int tn = (t + 2) & (CHT - 1);          // wraps on last iter; values unused
        short8 na0 = lA[tn * 64 + lane];
        short8 na1 = lA[tn * 64 + 64 + lane];
        {
            f32x16 c0 = MFMA(a0, bq0, z), c1 = MFMA(a1, bq0, z);
            #pragma unroll
            for (int i = 0; i < 16; ++i) vm0[i] = fminf(vm0[i], fminf(c0[i], c1[i]));
        }
        {
            f32x16 c0 = MFMA(a0, bq1, z), c1 = MFMA(a1, bq1, z);
            #pragma unroll
            for (int i = 0; i < 16; ++i) vm1[i] = fminf(vm1[i], fminf(c0[i], c1[i]));
        }
        a0 = na0; a1 = na1;
    }

    // Epilogue: horizontal min over 16 regs (tree), then xor-32 merge.
    int qbase = (dir * NB + b) * N + qp * 64;
    #pragma unroll
    for (int qi = 0; qi < 2; ++qi) {
        f32x16 vv = qi == 0 ? vm0 : vm1;
        float m0 = fminf(fminf(vv[0], vv[1]), fminf(vv[2], vv[3]));
        float m1 = fminf(fminf(vv[4], vv[5]), fminf(vv[6], vv[7]));
        float m2 = fminf(fminf(vv[8], vv[9]), fminf(vv[10], vv[11]));
        float m3 = fminf(fminf(vv[12], vv[13]), fminf(vv[14], vv[15]));
        float v = fminf(fminf(m0, m1), fminf(m2, m3));
        v = fminf(v, __shfl_xor(v, 32));
        if (lane < 32) {
            int gi = qbase + qi * 32 + lane;
            float d2 = fmaxf(v + p2s[gi], 0.f);   // clamp keeps uint-bit order valid
            atomicMin(&minsq[gi], __float_as_uint(d2));
        }
    }
}

// Fallback (ws too small / unexpected shape): direct f32 path, targets from global.
__global__ __launch_bounds__(THREADS) void nn_fallback_kernel(
    const float* __restrict__ pred, const float* __restrict__ gt,
    unsigned int* __restrict__ minsq, int N, int B, int nQC, int nTC, int blocksPerDir)
{
    int blk = blockIdx.x;
    int dir = blk / blocksPerDir;
    blk -= dir * blocksPerDir;
    int tc = blk % nTC;
    int qc = (blk / nTC) % nQC;
    int b  = blk / (nTC * nQC);
    const float* q = (dir ? gt : pred) + (size_t)b * 3 * N;
    const float* t = (dir ? pred : gt) + (size_t)b * 3 * N + tc * 256;
    float px[4], py[4], pz[4], p2[4], mn[4];
    int q0 = qc * 1024 + threadIdx.x;
    #pragma unroll
    for (int r = 0; r < 4; ++r) {
        int qi = q0 + r * THREADS;
        px[r] = -2.f * q[qi]; py[r] = -2.f * q[N + qi]; pz[r] = -2.f * q[2 * N + qi];
        p2[r] = fmaf(q[qi], q[qi], fmaf(q[N + qi], q[N + qi], q[2 * N + qi] * q[2 * N + qi]));
        mn[r] = 3.0e38f;
    }
    for (int j = 0; j < 256; j += 4) {
        float4 gx4 = *(const float4*)&t[j];
        float4 gy4 = *(const float4*)&t[N + j];
        float4 gz4 = *(const float4*)&t[2 * N + j];
        float g2_0 = fmaf(gx4.x, gx4.x, fmaf(gy4.x, gy4.x, gz4.x * gz4.x));
        float g2_1 = fmaf(gx4.y, gx4.y, fmaf(gy4.y, gy4.y, gz4.y * gz4.y));
        float g2_2 = fmaf(gx4.z, gx4.z, fmaf(gy4.z, gy4.z, gz4.z * gz4.z));
        float g2_3 = fmaf(gx4.w, gx4.w, fmaf(gy4.w, gy4.w, gz4.w * gz4.w));
        #pragma unroll
        for (int r = 0; r < 4; ++r) {
            float d0 = fmaf(gx4.x, px[r], fmaf(gy4.x, py[r], fmaf(gz4.x, pz[r], g2_0)));
            float d1 = fmaf(gx4.y, px[r], fmaf(gy4.y, py[r], fmaf(gz4.y, pz[r], g2_1)));
            float d2 = fmaf(gx4.z, px[r], fmaf(gy4.z, py[r], fmaf(gz4.z, pz[r], g2_2)));
            float d3 = fmaf(gx4.w, px[r], fmaf(gy4.w, py[r], fmaf(gz4.w, pz[r], g2_3)));
            mn[r] = fminf(fminf(d0, d1), mn[r]);
            mn[r] = fminf(fminf(d2, d3), mn[r]);
        }
    }
    unsigned int* mb = minsq + ((size_t)dir * B + b) * N;
    #pragma unroll
    for (int r = 0; r < 4; ++r) {
        float d2 = fmaxf(mn[r] + p2[r], 0.f);
        atomicMin(&mb[q0 + r * THREADS], __float_as_uint(d2));
    }
}

__global__ __launch_bounds__(THREADS) void reduce1_kernel(
    const unsigned int* __restrict__ minsq, float* __restrict__ partials, int total)
{
    __shared__ float sdata[THREADS];
    float s = 0.f;
    for (int i = blockIdx.x * THREADS + threadIdx.x; i < total; i += gridDim.x * THREADS) {
        float v = __uint_as_float(minsq[i]);
        s += sqrtf(v + 1e-8f);
    }
    sdata[threadIdx.x] = s;
    __syncthreads();
    for (int off = THREADS / 2; off > 0; off >>= 1) {
        if (threadIdx.x < off) sdata[threadIdx.x] += sdata[threadIdx.x + off];
        __syncthreads();
    }
    if (threadIdx.x == 0) partials[blockIdx.x] = sdata[0];
}

__global__ __launch_bounds__(64) void reduce2_kernel(
    const float* __restrict__ partials, float* __restrict__ out, float inv)
{
    float s = partials[threadIdx.x];
    #pragma unroll
    for (int off = 32; off > 0; off >>= 1) s += __shfl_down(s, off);
    if (threadIdx.x == 0) out[0] = s * inv;
}

extern "C" void kernel_launch(void* const* d_in, const int* in_sizes, int n_in,
                              void* d_out, int out_size, void* d_ws, size_t ws_size,
                              hipStream_t stream) {
    const float* pred = (const float*)d_in[0];
    const float* gt   = (const float*)d_in[1];
    const int N = 8192;
    const int B = in_sizes[0] / (3 * N);

    unsigned int* minsq = (unsigned int*)d_ws;
    int total = 2 * B * N;
    float* p2s      = (float*)((char*)d_ws + OFF_P2);
    float* partials = (float*)((char*)d_ws + OFF_PART);
    short8* sA      = (short8*)((char*)d_ws + OFF_SA);
    short8* sB      = (short8*)((char*)d_ws + OFF_SB);

    if (ws_size >= (size_t)WS_NEED && B == NB) {
        prep_kernel<<<total / THREADS, THREADS, 0, stream>>>(pred, gt, sA, sB, p2s, minsq, N);
        nn_mfma_kernel<<<2048, THREADS, 0, stream>>>(sA, sB, p2s, minsq, N);
    } else {
        hipMemsetAsync(minsq, 0x7F, (size_t)total * sizeof(unsigned int), stream);
        int nQC = N / 1024, nTC = N / 256;
        int blocksPerDir = B * nQC * nTC;
        nn_fallback_kernel<<<2 * blocksPerDir, THREADS, 0, stream>>>(
            pred, gt, minsq, N, B, nQC, nTC, blocksPerDir);
    }

    reduce1_kernel<<<64, THREADS, 0, stream>>>(minsq, partials, total);
    reduce2_kernel<<<1, 64, 0, stream>>>(partials, (float*)d_out, 1.0f / (B * N));
}

// Round 12
// 32.592 us; speedup vs baseline: 2.0820x; 1.0010x over previous
//
#include <hip/hip_runtime.h>

#define THREADS 256
#define NB 4                 // batches
#define NPTS 8192            // points per cloud
#define CHT 32               // A-tiles per LDS chunk (32 KB)

typedef __attribute__((ext_vector_type(8))) short short8;   // 8 bf16 = 4 VGPR
typedef __attribute__((ext_vector_type(16))) float f32x16;  // MFMA 32x32 acc

__device__ inline unsigned short f2b(float f) {  // f32 -> bf16 RNE (no NaN inputs here)
    unsigned u = __float_as_uint(f);
    return (unsigned short)((u + 0x7FFFu + ((u >> 16) & 1u)) >> 16);
}
__device__ inline float b2f(unsigned short h) {
    return __uint_as_float(((unsigned)h) << 16);
}

#define MFMA(a, b, c) __builtin_amdgcn_mfma_f32_32x32x16_bf16(a, b, c, 0, 0, 0)

// Fragment K-slot plan (verified absmax=0 rounds 7-11):
// A (targets, rows; lane row=l&31, kgrp=l>>5):
//   kgrp0: [ghx ghy ghz glx gly glz ghx ghy]  kgrp1: [ghz g2h g2l 0 0 0 0 0]
// B (queries, cols; a=split(-2p)):
//   kgrp0: [ahx ahy ahz ahx ahy ahz alx aly]  kgrp1: [alz 1 1 0 0 0 0 0]
// => acc[target][query] = |g|^2 - 2 p.g  (+|p|^2 in epilogue)

// Fused: stage A-chunk fragments in LDS straight from raw coords; B-frags in reg.
// block = (dir, b, chunk, qpg); 4 waves each own one query pair vs the chunk.
__global__ __launch_bounds__(THREADS, 4) void nn_fused_kernel(
    const float* __restrict__ pred, const float* __restrict__ gt,
    unsigned int* __restrict__ minsq, int N)
{
    __shared__ short8 lA[CHT * 64];   // 32 KB

    int wave = threadIdx.x >> 6;
    int lane = threadIdx.x & 63;
    int blk = blockIdx.x;             // [0, 2048)
    int dir   = blk >> 10;
    int b     = (blk >> 8) & 3;
    int chunk = (blk >> 5) & 7;       // 8 chunks of 32 tiles (1024 targets)
    int qpg   = blk & 31;             // 32 query-pair groups (x4 waves)

    const float* q = (dir ? gt : pred) + (size_t)b * 3 * N;  // queries
    const float* t = (dir ? pred : gt) + (size_t)b * 3 * N;  // targets

    // ---- stage A-chunk: 1024 targets, 4 per thread, coalesced in jj ----
    int cbase = chunk * (CHT * 32);
    #pragma unroll
    for (int k = 0; k < 4; ++k) {
        int jj = k * THREADS + threadIdx.x;      // [0,1024)
        int j  = cbase + jj;
        float gx = t[j], gy = t[N + j], gz = t[2 * N + j];
        unsigned short ghx = f2b(gx), ghy = f2b(gy), ghz = f2b(gz);
        unsigned short glx = f2b(gx - b2f(ghx)), gly = f2b(gy - b2f(ghy)), glz = f2b(gz - b2f(ghz));
        float g2 = fmaf(gx, gx, fmaf(gy, gy, gz * gz));
        unsigned short g2h = f2b(g2), g2l = f2b(g2 - b2f(g2h));
        short8 ta0, ta1;
        ta0[0]=(short)ghx; ta0[1]=(short)ghy; ta0[2]=(short)ghz; ta0[3]=(short)glx;
        ta0[4]=(short)gly; ta0[5]=(short)glz; ta0[6]=(short)ghx; ta0[7]=(short)ghy;
        ta1[0]=(short)ghz; ta1[1]=(short)g2h; ta1[2]=(short)g2l; ta1[3]=0;
        ta1[4]=0; ta1[5]=0; ta1[6]=0; ta1[7]=0;
        int tile = jj >> 5, c = jj & 31;
        lA[tile * 64 + c]      = ta0;
        lA[tile * 64 + 32 + c] = ta1;
    }

    // ---- build this wave's B-fragments (2 query tiles) + |p|^2 ----
    int qp = qpg * 4 + wave;                 // query pair [0,128)
    int hi = lane >> 5;
    int qj0 = qp * 64 + (lane & 31);         // tile 2qp,   col lane&31
    int qj1 = qj0 + 32;                      // tile 2qp+1, col lane&31
    const short ONE = (short)0x3F80;

    short8 bq0, bq1;
    float p20, p21;
    {
        float px = q[qj0], py = q[N + qj0], pz = q[2 * N + qj0];
        p20 = fmaf(px, px, fmaf(py, py, pz * pz));
        float ax = -2.f * px, ay = -2.f * py, az = -2.f * pz;
        unsigned short ahx = f2b(ax), ahy = f2b(ay), ahz = f2b(az);
        unsigned short alx = f2b(ax - b2f(ahx)), aly = f2b(ay - b2f(ahy)), alz = f2b(az - b2f(ahz));
        short8 v0, v1;
        v0[0]=(short)ahx; v0[1]=(short)ahy; v0[2]=(short)ahz; v0[3]=(short)ahx;
        v0[4]=(short)ahy; v0[5]=(short)ahz; v0[6]=(short)alx; v0[7]=(short)aly;
        v1[0]=(short)alz; v1[1]=ONE; v1[2]=ONE; v1[3]=0; v1[4]=0; v1[5]=0; v1[6]=0; v1[7]=0;
        bq0 = hi ? v1 : v0;
    }
    {
        float px = q[qj1], py = q[N + qj1], pz = q[2 * N + qj1];
        p21 = fmaf(px, px, fmaf(py, py, pz * pz));
        float ax = -2.f * px, ay = -2.f * py, az = -2.f * pz;
        unsigned short ahx = f2b(ax), ahy = f2b(ay), ahz = f2b(az);
        unsigned short alx = f2b(ax - b2f(ahx)), aly = f2b(ay - b2f(ahy)), alz = f2b(az - b2f(ahz));
        short8 v0, v1;
        v0[0]=(short)ahx; v0[1]=(short)ahy; v0[2]=(short)ahz; v0[3]=(short)ahx;
        v0[4]=(short)ahy; v0[5]=(short)ahz; v0[6]=(short)alx; v0[7]=(short)aly;
        v1[0]=(short)alz; v1[1]=ONE; v1[2]=ONE; v1[3]=0; v1[4]=0; v1[5]=0; v1[6]=0; v1[7]=0;
        bq1 = hi ? v1 : v0;
    }

    f32x16 z;
    #pragma unroll
    for (int i = 0; i < 16; ++i) z[i] = 0.f;

    f32x16 vm0, vm1;
    #pragma unroll
    for (int i = 0; i < 16; ++i) { vm0[i] = 3.0e38f; vm1[i] = 3.0e38f; }

    __syncthreads();

    // ---- main loop: no SW pipeline (TLP covers LDS latency); tight registers ----
    for (int tt = 0; tt < CHT; tt += 2) {
        short8 a0 = lA[tt * 64 + lane];
        short8 a1 = lA[tt * 64 + 64 + lane];
        {
            f32x16 c0 = MFMA(a0, bq0, z), c1 = MFMA(a1, bq0, z);
            #pragma unroll
            for (int i = 0; i < 16; ++i) vm0[i] = fminf(vm0[i], fminf(c0[i], c1[i]));
        }
        {
            f32x16 c0 = MFMA(a0, bq1, z), c1 = MFMA(a1, bq1, z);
            #pragma unroll
            for (int i = 0; i < 16; ++i) vm1[i] = fminf(vm1[i], fminf(c0[i], c1[i]));
        }
    }

    // ---- epilogue: horizontal min (tree) + xor-32 merge + atomicMin ----
    int qbase = (dir * NB + b) * N + qp * 64;
    #pragma unroll
    for (int qi = 0; qi < 2; ++qi) {
        f32x16 vv = qi == 0 ? vm0 : vm1;
        float p2 = qi == 0 ? p20 : p21;
        float m0 = fminf(fminf(vv[0], vv[1]), fminf(vv[2], vv[3]));
        float m1 = fminf(fminf(vv[4], vv[5]), fminf(vv[6], vv[7]));
        float m2 = fminf(fminf(vv[8], vv[9]), fminf(vv[10], vv[11]));
        float m3 = fminf(fminf(vv[12], vv[13]), fminf(vv[14], vv[15]));
        float v = fminf(fminf(m0, m1), fminf(m2, m3));
        v = fminf(v, __shfl_xor(v, 32));
        if (lane < 32) {
            float d2 = fmaxf(v + p2, 0.f);   // clamp keeps uint-bit order valid
            atomicMin(&minsq[qbase + qi * 32 + lane], __float_as_uint(d2));
        }
    }
}

// Fallback (unexpected shape): direct f32 path, targets from global.
__global__ __launch_bounds__(THREADS) void nn_fallback_kernel(
    const float* __restrict__ pred, const float* __restrict__ gt,
    unsigned int* __restrict__ minsq, int N, int B, int nQC, int nTC, int blocksPerDir)
{
    int blk = blockIdx.x;
    int dir = blk / blocksPerDir;
    blk -= dir * blocksPerDir;
    int tc = blk % nTC;
    int qc = (blk / nTC) % nQC;
    int b  = blk / (nTC * nQC);
    const float* q = (dir ? gt : pred) + (size_t)b * 3 * N;
    const float* t = (dir ? pred : gt) + (size_t)b * 3 * N + tc * 256;
    float px[4], py[4], pz[4], p2[4], mn[4];
    int q0 = qc * 1024 + threadIdx.x;
    #pragma unroll
    for (int r = 0; r < 4; ++r) {
        int qi = q0 + r * THREADS;
        px[r] = -2.f * q[qi]; py[r] = -2.f * q[N + qi]; pz[r] = -2.f * q[2 * N + qi];
        p2[r] = fmaf(q[qi], q[qi], fmaf(q[N + qi], q[N + qi], q[2 * N + qi] * q[2 * N + qi]));
        mn[r] = 3.0e38f;
    }
    for (int j = 0; j < 256; j += 4) {
        float4 gx4 = *(const float4*)&t[j];
        float4 gy4 = *(const float4*)&t[N + j];
        float4 gz4 = *(const float4*)&t[2 * N + j];
        float g2_0 = fmaf(gx4.x, gx4.x, fmaf(gy4.x, gy4.x, gz4.x * gz4.x));
        float g2_1 = fmaf(gx4.y, gx4.y, fmaf(gy4.y, gy4.y, gz4.y * gz4.y));
        float g2_2 = fmaf(gx4.z, gx4.z, fmaf(gy4.z, gy4.z, gz4.z * gz4.z));
        float g2_3 = fmaf(gx4.w, gx4.w, fmaf(gy4.w, gy4.w, gz4.w * gz4.w));
        #pragma unroll
        for (int r = 0; r < 4; ++r) {
            float d0 = fmaf(gx4.x, px[r], fmaf(gy4.x, py[r], fmaf(gz4.x, pz[r], g2_0)));
            float d1 = fmaf(gx4.y, px[r], fmaf(gy4.y, py[r], fmaf(gz4.y, pz[r], g2_1)));
            float d2 = fmaf(gx4.z, px[r], fmaf(gy4.z, py[r], fmaf(gz4.z, pz[r], g2_2)));
            float d3 = fmaf(gx4.w, px[r], fmaf(gy4.w, py[r], fmaf(gz4.w, pz[r], g2_3)));
            mn[r] = fminf(fminf(d0, d1), mn[r]);
            mn[r] = fminf(fminf(d2, d3), mn[r]);
        }
    }
    unsigned int* mb = minsq + ((size_t)dir * B + b) * N;
    #pragma unroll
    for (int r = 0; r < 4; ++r) {
        float d2 = fmaxf(mn[r] + p2[r], 0.f);
        atomicMin(&mb[q0 + r * THREADS], __float_as_uint(d2));
    }
}

__global__ __launch_bounds__(THREADS) void reduce1_kernel(
    const unsigned int* __restrict__ minsq, float* __restrict__ partials, int total)
{
    __shared__ float sdata[THREADS];
    float s = 0.f;
    for (int i = blockIdx.x * THREADS + threadIdx.x; i < total; i += gridDim.x * THREADS) {
        float v = __uint_as_float(minsq[i]);
        s += sqrtf(v + 1e-8f);
    }
    sdata[threadIdx.x] = s;
    __syncthreads();
    for (int off = THREADS / 2; off > 0; off >>= 1) {
        if (threadIdx.x < off) sdata[threadIdx.x] += sdata[threadIdx.x + off];
        __syncthreads();
    }
    if (threadIdx.x == 0) partials[blockIdx.x] = sdata[0];
}

__global__ __launch_bounds__(64) void reduce2_kernel(
    const float* __restrict__ partials, float* __restrict__ out, float inv)
{
    float s = partials[threadIdx.x];
    #pragma unroll
    for (int off = 32; off > 0; off >>= 1) s += __shfl_down(s, off);
    if (threadIdx.x == 0) out[0] = s * inv;
}

extern "C" void kernel_launch(void* const* d_in, const int* in_sizes, int n_in,
                              void* d_out, int out_size, void* d_ws, size_t ws_size,
                              hipStream_t stream) {
    const float* pred = (const float*)d_in[0];
    const float* gt   = (const float*)d_in[1];
    const int N = 8192;
    const int B = in_sizes[0] / (3 * N);

    unsigned int* minsq = (unsigned int*)d_ws;            // 2*B*N uints = 256 KB
    int total = 2 * B * N;
    float* partials = (float*)((char*)d_ws + (512 << 10));  // 64 floats

    hipMemsetAsync(minsq, 0x7F, (size_t)total * sizeof(unsigned int), stream);

    if (B == NB && N == NPTS) {
        nn_fused_kernel<<<2048, THREADS, 0, stream>>>(pred, gt, minsq, N);
    } else {
        int nQC = N / 1024, nTC = N / 256;
        int blocksPerDir = B * nQC * nTC;
        nn_fallback_kernel<<<2 * blocksPerDir, THREADS, 0, stream>>>(
            pred, gt, minsq, N, B, nQC, nTC, blocksPerDir);
    }

    reduce1_kernel<<<64, THREADS, 0, stream>>>(minsq, partials, total);
    reduce2_kernel<<<1, 64, 0, stream>>>(partials, (float*)d_out, 1.0f / (B * N));
}

// Round 13
// 28.911 us; speedup vs baseline: 2.3471x; 1.1273x over previous
//
#include <hip/hip_runtime.h>

#define THREADS 256
#define NB 4                 // batches
#define NPTS 8192            // points per cloud
#define CHT 32               // A-tiles per LDS chunk (32 KB)
#define NCH 8                // target chunks per (dir,b)

typedef __attribute__((ext_vector_type(8))) short short8;   // 8 bf16 = 4 VGPR
typedef __attribute__((ext_vector_type(16))) float f32x16;  // MFMA 32x32 acc

__device__ inline unsigned short f2b(float f) {  // f32 -> bf16 RNE (no NaN inputs here)
    unsigned u = __float_as_uint(f);
    return (unsigned short)((u + 0x7FFFu + ((u >> 16) & 1u)) >> 16);
}
__device__ inline float b2f(unsigned short h) {
    return __uint_as_float(((unsigned)h) << 16);
}

// Fragment K-slot plan (verified absmax=0 rounds 7-12):
// A (targets, rows; lane row=l&31, kgrp=l>>5):
//   kgrp0: [ghx ghy ghz glx gly glz ghx ghy]  kgrp1: [ghz g2h g2l 0 0 0 0 0]
// B (queries, cols; a=split(-2p)):
//   kgrp0: [ahx ahy ahz ahx ahy ahz alx aly]  kgrp1: [alz 1 1 0 0 0 0 0]
// => acc[target][query] = |g|^2 - 2 p.g  (+|p|^2 in epilogue)

// Inline-asm MFMA pair with VGPR destinations (kills v_accvgpr_* copies around
// the min3 consumers). s_nop 7+7+1 = 18 wait states cover the 16-pass-MFMA ->
// VALU-read hazard (hazard recognizer can't see into asm, so we pay it here).
#define MFMA_PAIR(c0, c1, a0, a1, bq, z)                                   \
    asm("v_mfma_f32_32x32x16_bf16 %0, %2, %4, %5\n\t"                      \
        "v_mfma_f32_32x32x16_bf16 %1, %3, %4, %5\n\t"                      \
        "s_nop 7\n\t"                                                      \
        "s_nop 7\n\t"                                                      \
        "s_nop 1"                                                          \
        : "=&v"(c0), "=&v"(c1)                                             \
        : "v"(a0), "v"(a1), "v"(bq), "v"(z))

// Fused: stage A-chunk fragments in LDS from raw coords; B-frags in registers.
// block = (dir, b, chunk, qpg); 4 waves each own one query pair vs the chunk.
// No atomics: per-(query,chunk) partial min stored to pmin[gi*8+chunk].
__global__ __launch_bounds__(THREADS, 4) void nn_fused_kernel(
    const float* __restrict__ pred, const float* __restrict__ gt,
    float* __restrict__ pmin, int N)
{
    __shared__ short8 lA[CHT * 64];   // 32 KB

    int wave = threadIdx.x >> 6;
    int lane = threadIdx.x & 63;
    int blk = blockIdx.x;             // [0, 2048)
    int dir   = blk >> 10;
    int b     = (blk >> 8) & 3;
    int chunk = (blk >> 5) & 7;       // 8 chunks of 32 tiles (1024 targets)
    int qpg   = blk & 31;             // 32 query-pair groups (x4 waves)

    const float* q = (dir ? gt : pred) + (size_t)b * 3 * N;  // queries
    const float* t = (dir ? pred : gt) + (size_t)b * 3 * N;  // targets

    // ---- stage A-chunk: 1024 targets, 4 per thread, coalesced in jj ----
    int cbase = chunk * (CHT * 32);
    #pragma unroll
    for (int k = 0; k < 4; ++k) {
        int jj = k * THREADS + threadIdx.x;      // [0,1024)
        int j  = cbase + jj;
        float gx = t[j], gy = t[N + j], gz = t[2 * N + j];
        unsigned short ghx = f2b(gx), ghy = f2b(gy), ghz = f2b(gz);
        unsigned short glx = f2b(gx - b2f(ghx)), gly = f2b(gy - b2f(ghy)), glz = f2b(gz - b2f(ghz));
        float g2 = fmaf(gx, gx, fmaf(gy, gy, gz * gz));
        unsigned short g2h = f2b(g2), g2l = f2b(g2 - b2f(g2h));
        short8 ta0, ta1;
        ta0[0]=(short)ghx; ta0[1]=(short)ghy; ta0[2]=(short)ghz; ta0[3]=(short)glx;
        ta0[4]=(short)gly; ta0[5]=(short)glz; ta0[6]=(short)ghx; ta0[7]=(short)ghy;
        ta1[0]=(short)ghz; ta1[1]=(short)g2h; ta1[2]=(short)g2l; ta1[3]=0;
        ta1[4]=0; ta1[5]=0; ta1[6]=0; ta1[7]=0;
        int tile = jj >> 5, c = jj & 31;
        lA[tile * 64 + c]      = ta0;
        lA[tile * 64 + 32 + c] = ta1;
    }

    // ---- build this wave's B-fragments (2 query tiles) + |p|^2 ----
    int qp = qpg * 4 + wave;                 // query pair [0,128)
    int hi = lane >> 5;
    int qj0 = qp * 64 + (lane & 31);         // tile 2qp,   col lane&31
    int qj1 = qj0 + 32;                      // tile 2qp+1, col lane&31
    const short ONE = (short)0x3F80;

    short8 bq0, bq1;
    float p20, p21;
    {
        float px = q[qj0], py = q[N + qj0], pz = q[2 * N + qj0];
        p20 = fmaf(px, px, fmaf(py, py, pz * pz));
        float ax = -2.f * px, ay = -2.f * py, az = -2.f * pz;
        unsigned short ahx = f2b(ax), ahy = f2b(ay), ahz = f2b(az);
        unsigned short alx = f2b(ax - b2f(ahx)), aly = f2b(ay - b2f(ahy)), alz = f2b(az - b2f(ahz));
        short8 v0, v1;
        v0[0]=(short)ahx; v0[1]=(short)ahy; v0[2]=(short)ahz; v0[3]=(short)ahx;
        v0[4]=(short)ahy; v0[5]=(short)ahz; v0[6]=(short)alx; v0[7]=(short)aly;
        v1[0]=(short)alz; v1[1]=ONE; v1[2]=ONE; v1[3]=0; v1[4]=0; v1[5]=0; v1[6]=0; v1[7]=0;
        bq0 = hi ? v1 : v0;
    }
    {
        float px = q[qj1], py = q[N + qj1], pz = q[2 * N + qj1];
        p21 = fmaf(px, px, fmaf(py, py, pz * pz));
        float ax = -2.f * px, ay = -2.f * py, az = -2.f * pz;
        unsigned short ahx = f2b(ax), ahy = f2b(ay), ahz = f2b(az);
        unsigned short alx = f2b(ax - b2f(ahx)), aly = f2b(ay - b2f(ahy)), alz = f2b(az - b2f(ahz));
        short8 v0, v1;
        v0[0]=(short)ahx; v0[1]=(short)ahy; v0[2]=(short)ahz; v0[3]=(short)ahx;
        v0[4]=(short)ahy; v0[5]=(short)ahz; v0[6]=(short)alx; v0[7]=(short)aly;
        v1[0]=(short)alz; v1[1]=ONE; v1[2]=ONE; v1[3]=0; v1[4]=0; v1[5]=0; v1[6]=0; v1[7]=0;
        bq1 = hi ? v1 : v0;
    }

    f32x16 z;
    #pragma unroll
    for (int i = 0; i < 16; ++i) z[i] = 0.f;

    f32x16 vm0, vm1;
    #pragma unroll
    for (int i = 0; i < 16; ++i) { vm0[i] = 3.0e38f; vm1[i] = 3.0e38f; }

    __syncthreads();

    // ---- main loop ----
    for (int tt = 0; tt < CHT; tt += 2) {
        short8 a0 = lA[tt * 64 + lane];
        short8 a1 = lA[tt * 64 + 64 + lane];
        {
            f32x16 c0, c1;
            MFMA_PAIR(c0, c1, a0, a1, bq0, z);
            #pragma unroll
            for (int i = 0; i < 16; ++i) vm0[i] = fminf(vm0[i], fminf(c0[i], c1[i]));
        }
        {
            f32x16 c0, c1;
            MFMA_PAIR(c0, c1, a0, a1, bq1, z);
            #pragma unroll
            for (int i = 0; i < 16; ++i) vm1[i] = fminf(vm1[i], fminf(c0[i], c1[i]));
        }
    }

    // ---- epilogue: horizontal min (tree) + xor-32 merge + partial store ----
    int qbase = (dir * NB + b) * N + qp * 64;
    #pragma unroll
    for (int qi = 0; qi < 2; ++qi) {
        f32x16 vv = qi == 0 ? vm0 : vm1;
        float p2 = qi == 0 ? p20 : p21;
        float m0 = fminf(fminf(vv[0], vv[1]), fminf(vv[2], vv[3]));
        float m1 = fminf(fminf(vv[4], vv[5]), fminf(vv[6], vv[7]));
        float m2 = fminf(fminf(vv[8], vv[9]), fminf(vv[10], vv[11]));
        float m3 = fminf(fminf(vv[12], vv[13]), fminf(vv[14], vv[15]));
        float v = fminf(fminf(m0, m1), fminf(m2, m3));
        v = fminf(v, __shfl_xor(v, 32));
        if (lane < 32) {
            pmin[(size_t)(qbase + qi * 32 + lane) * NCH + chunk] = fmaxf(v + p2, 0.f);
        }
    }
}

// reduce1 (main path): 8-way chunk min + sqrt + per-block sum
__global__ __launch_bounds__(THREADS) void reduce1_pmin_kernel(
    const float* __restrict__ pmin, float* __restrict__ partials, int totalQ)
{
    __shared__ float sdata[THREADS];
    float s = 0.f;
    for (int gi = blockIdx.x * THREADS + threadIdx.x; gi < totalQ; gi += gridDim.x * THREADS) {
        const float4* p = (const float4*)(pmin + (size_t)gi * NCH);
        float4 u = p[0], w = p[1];
        float m = fminf(fminf(fminf(u.x, u.y), fminf(u.z, u.w)),
                        fminf(fminf(w.x, w.y), fminf(w.z, w.w)));
        s += sqrtf(m + 1e-8f);
    }
    sdata[threadIdx.x] = s;
    __syncthreads();
    for (int off = THREADS / 2; off > 0; off >>= 1) {
        if (threadIdx.x < off) sdata[threadIdx.x] += sdata[threadIdx.x + off];
        __syncthreads();
    }
    if (threadIdx.x == 0) partials[blockIdx.x] = sdata[0];
}

// Fallback (unexpected shape): direct f32 path + atomicMin on uint bits.
__global__ __launch_bounds__(THREADS) void nn_fallback_kernel(
    const float* __restrict__ pred, const float* __restrict__ gt,
    unsigned int* __restrict__ minsq, int N, int B, int nQC, int nTC, int blocksPerDir)
{
    int blk = blockIdx.x;
    int dir = blk / blocksPerDir;
    blk -= dir * blocksPerDir;
    int tc = blk % nTC;
    int qc = (blk / nTC) % nQC;
    int b  = blk / (nTC * nQC);
    const float* q = (dir ? gt : pred) + (size_t)b * 3 * N;
    const float* t = (dir ? pred : gt) + (size_t)b * 3 * N + tc * 256;
    float px[4], py[4], pz[4], p2[4], mn[4];
    int q0 = qc * 1024 + threadIdx.x;
    #pragma unroll
    for (int r = 0; r < 4; ++r) {
        int qi = q0 + r * THREADS;
        px[r] = -2.f * q[qi]; py[r] = -2.f * q[N + qi]; pz[r] = -2.f * q[2 * N + qi];
        p2[r] = fmaf(q[qi], q[qi], fmaf(q[N + qi], q[N + qi], q[2 * N + qi] * q[2 * N + qi]));
        mn[r] = 3.0e38f;
    }
    for (int j = 0; j < 256; j += 4) {
        float4 gx4 = *(const float4*)&t[j];
        float4 gy4 = *(const float4*)&t[N + j];
        float4 gz4 = *(const float4*)&t[2 * N + j];
        float g2_0 = fmaf(gx4.x, gx4.x, fmaf(gy4.x, gy4.x, gz4.x * gz4.x));
        float g2_1 = fmaf(gx4.y, gx4.y, fmaf(gy4.y, gy4.y, gz4.y * gz4.y));
        float g2_2 = fmaf(gx4.z, gx4.z, fmaf(gy4.z, gy4.z, gz4.z * gz4.z));
        float g2_3 = fmaf(gx4.w, gx4.w, fmaf(gy4.w, gy4.w, gz4.w * gz4.w));
        #pragma unroll
        for (int r = 0; r < 4; ++r) {
            float d0 = fmaf(gx4.x, px[r], fmaf(gy4.x, py[r], fmaf(gz4.x, pz[r], g2_0)));
            float d1 = fmaf(gx4.y, px[r], fmaf(gy4.y, py[r], fmaf(gz4.y, pz[r], g2_1)));
            float d2 = fmaf(gx4.z, px[r], fmaf(gy4.z, py[r], fmaf(gz4.z, pz[r], g2_2)));
            float d3 = fmaf(gx4.w, px[r], fmaf(gy4.w, py[r], fmaf(gz4.w, pz[r], g2_3)));
            mn[r] = fminf(fminf(d0, d1), mn[r]);
            mn[r] = fminf(fminf(d2, d3), mn[r]);
        }
    }
    unsigned int* mb = minsq + ((size_t)dir * B + b) * N;
    #pragma unroll
    for (int r = 0; r < 4; ++r) {
        float d2 = fmaxf(mn[r] + p2[r], 0.f);
        atomicMin(&mb[q0 + r * THREADS], __float_as_uint(d2));
    }
}

__global__ __launch_bounds__(THREADS) void reduce1_direct_kernel(
    const unsigned int* __restrict__ minsq, float* __restrict__ partials, int total)
{
    __shared__ float sdata[THREADS];
    float s = 0.f;
    for (int i = blockIdx.x * THREADS + threadIdx.x; i < total; i += gridDim.x * THREADS) {
        float v = __uint_as_float(minsq[i]);
        s += sqrtf(v + 1e-8f);
    }
    sdata[threadIdx.x] = s;
    __syncthreads();
    for (int off = THREADS / 2; off > 0; off >>= 1) {
        if (threadIdx.x < off) sdata[threadIdx.x] += sdata[threadIdx.x + off];
        __syncthreads();
    }
    if (threadIdx.x == 0) partials[blockIdx.x] = sdata[0];
}

__global__ __launch_bounds__(64) void reduce2_kernel(
    const float* __restrict__ partials, float* __restrict__ out, float inv)
{
    float s = partials[threadIdx.x];
    #pragma unroll
    for (int off = 32; off > 0; off >>= 1) s += __shfl_down(s, off);
    if (threadIdx.x == 0) out[0] = s * inv;
}

extern "C" void kernel_launch(void* const* d_in, const int* in_sizes, int n_in,
                              void* d_out, int out_size, void* d_ws, size_t ws_size,
                              hipStream_t stream) {
    const float* pred = (const float*)d_in[0];
    const float* gt   = (const float*)d_in[1];
    const int N = 8192;
    const int B = in_sizes[0] / (3 * N);
    int totalQ = 2 * B * N;                               // 65536

    float* pmin     = (float*)d_ws;                       // 2*B*N*8 floats = 2 MB
    float* partials = (float*)((char*)d_ws + (4 << 20));  // 64 floats

    if (B == NB && N == NPTS) {
        nn_fused_kernel<<<2048, THREADS, 0, stream>>>(pred, gt, pmin, N);
        reduce1_pmin_kernel<<<64, THREADS, 0, stream>>>(pmin, partials, totalQ);
    } else {
        unsigned int* minsq = (unsigned int*)d_ws;
        hipMemsetAsync(minsq, 0x7F, (size_t)totalQ * sizeof(unsigned int), stream);
        int nQC = N / 1024, nTC = N / 256;
        int blocksPerDir = B * nQC * nTC;
        nn_fallback_kernel<<<2 * blocksPerDir, THREADS, 0, stream>>>(
            pred, gt, minsq, N, B, nQC, nTC, blocksPerDir);
        reduce1_direct_kernel<<<64, THREADS, 0, stream>>>(minsq, partials, totalQ);
    }

    reduce2_kernel<<<1, 64, 0, stream>>>(partials, (float*)d_out, 1.0f / (B * N));
}